// Round 1
// baseline (991.203 us; speedup 1.0000x reference)
//
#include <hip/hip_runtime.h>
#include <hip/hip_bf16.h>

#define B_    2
#define T_    2048
#define D_    1024
#define H_    16
#define DK_   64
#define BH_   (B_*H_)
#define M_    (B_*T_)        // 4096 GEMM rows
#define NSTEP 5
#define DT_   0.1f
#define TWO_PI_F 6.28318530717958647692f

typedef __attribute__((ext_vector_type(8))) short s16x8;   // 8 bf16 (4 VGPRs)
typedef __attribute__((ext_vector_type(4))) float f32x4;

__device__ __forceinline__ unsigned short f2bf(float f) {
  unsigned int u = __float_as_uint(f);
  u += 0x7FFFu + ((u >> 16) & 1u);       // round-to-nearest-even
  return (unsigned short)(u >> 16);
}

// ---------------------------------------------------------------------------
// GEMM: Y[m,n] = sum_k A[m,k] * W[n,k];  A: M_ x 1024 f32, W: 1024 x 1024 f32
// (both operands k-contiguous). MODE 0: store bf16(Y*scale). MODE 1: f32.
// MODE 2: f32(Y + res).  128x128 tile, 4 waves, 16x16x32 bf16 MFMA.
// ---------------------------------------------------------------------------
template<int MODE>
__global__ __launch_bounds__(256)
void gemm128(const float* __restrict__ A, const float* __restrict__ W,
             void* __restrict__ outp, const float* __restrict__ res, float scale)
{
  __shared__ short lA[128*32];
  __shared__ short lB[128*32];
  const int m0 = blockIdx.x * 128;
  const int n0 = blockIdx.y * 128;
  const int t  = threadIdx.x;
  const int wv = t >> 6;
  const int lane = t & 63;
  const int wm = wv >> 1, wn = wv & 1;
  const int lr = lane & 15, kg = lane >> 4;

  f32x4 acc[4][4];
#pragma unroll
  for (int i = 0; i < 4; ++i)
#pragma unroll
    for (int j = 0; j < 4; ++j) {
      acc[i][j][0] = 0.f; acc[i][j][1] = 0.f; acc[i][j][2] = 0.f; acc[i][j][3] = 0.f;
    }

  const int srow = t >> 2;    // 0..63
  const int sc   = t & 3;     // 16B chunk within 64B LDS row

  for (int kt = 0; kt < 1024; kt += 32) {
#pragma unroll
    for (int p = 0; p < 2; ++p) {
      int row = srow + p*64;
      int bo  = row*64 + ((sc*16) ^ ((row & 3) << 4));   // swizzled byte offset
      const float4* ga = (const float4*)(A + (size_t)(m0+row)*1024 + kt + sc*8);
      float4 a0 = ga[0], a1 = ga[1];
      s16x8 ha;
      ha[0]=(short)f2bf(a0.x); ha[1]=(short)f2bf(a0.y); ha[2]=(short)f2bf(a0.z); ha[3]=(short)f2bf(a0.w);
      ha[4]=(short)f2bf(a1.x); ha[5]=(short)f2bf(a1.y); ha[6]=(short)f2bf(a1.z); ha[7]=(short)f2bf(a1.w);
      *(s16x8*)((char*)lA + bo) = ha;
      const float4* gb = (const float4*)(W + (size_t)(n0+row)*1024 + kt + sc*8);
      float4 b0 = gb[0], b1 = gb[1];
      s16x8 hb;
      hb[0]=(short)f2bf(b0.x); hb[1]=(short)f2bf(b0.y); hb[2]=(short)f2bf(b0.z); hb[3]=(short)f2bf(b0.w);
      hb[4]=(short)f2bf(b1.x); hb[5]=(short)f2bf(b1.y); hb[6]=(short)f2bf(b1.z); hb[7]=(short)f2bf(b1.w);
      *(s16x8*)((char*)lB + bo) = hb;
    }
    __syncthreads();

    s16x8 af[4], bfr[4];
#pragma unroll
    for (int mf = 0; mf < 4; ++mf) {
      int row = wm*64 + mf*16 + lr;
      af[mf] = *(const s16x8*)((const char*)lA + row*64 + ((kg*16) ^ ((row & 3) << 4)));
    }
#pragma unroll
    for (int nf = 0; nf < 4; ++nf) {
      int row = wn*64 + nf*16 + lr;
      bfr[nf] = *(const s16x8*)((const char*)lB + row*64 + ((kg*16) ^ ((row & 3) << 4)));
    }
#pragma unroll
    for (int mf = 0; mf < 4; ++mf)
#pragma unroll
      for (int nf = 0; nf < 4; ++nf)
        acc[mf][nf] = __builtin_amdgcn_mfma_f32_16x16x32_bf16(af[mf], bfr[nf], acc[mf][nf], 0, 0, 0);
    __syncthreads();
  }

#pragma unroll
  for (int mf = 0; mf < 4; ++mf)
#pragma unroll
    for (int nf = 0; nf < 4; ++nf)
#pragma unroll
      for (int r = 0; r < 4; ++r) {
        int grow = m0 + wm*64 + mf*16 + kg*4 + r;   // C/D: row=(lane>>4)*4+reg
        int gcol = n0 + wn*64 + nf*16 + lr;         //      col=lane&15
        size_t o = (size_t)grow*1024 + gcol;
        float v = acc[mf][nf][r];
        if (MODE == 0)      ((unsigned short*)outp)[o] = f2bf(v*scale);
        else if (MODE == 1) ((float*)outp)[o] = v;
        else                ((float*)outp)[o] = v + res[o];
      }
}

// ---------------------------------------------------------------------------
// Exact f32 dot products for the 2 phase-relevant V columns per head.
// V01[row][2h+c] = sum_k x[row,k]*Wv[h*64+c, k].  (atan2 is error-amplifying
// when both components are tiny; bf16 GEMM error would blow the threshold.)
// ---------------------------------------------------------------------------
__global__ __launch_bounds__(256)
void v01_kernel(const float* __restrict__ x, const float* __restrict__ Wv,
                float* __restrict__ V01)
{
  const int t = threadIdx.x;
  const int colid = t & 31;               // h = colid>>1, comp = colid&1
  const int row = blockIdx.x*8 + (t >> 5);
  const int wcol = (colid >> 1)*DK_ + (colid & 1);
  const float4* xr = (const float4*)(x  + (size_t)row*1024);
  const float4* wr = (const float4*)(Wv + (size_t)wcol*1024);
  float acc = 0.f;
  for (int k = 0; k < 256; ++k) {
    float4 a = xr[k], b = wr[k];
    acc += a.x*b.x + a.y*b.y + a.z*b.z + a.w*b.w;
  }
  V01[(size_t)row*32 + colid] = acc;
}

__global__ void phase_init(const float* __restrict__ V01, float* __restrict__ ph)
{
  int idx = blockIdx.x*256 + threadIdx.x;  // over B*H*T
  int tt = idx & (T_-1);
  int bh = idx >> 11;
  int b = bh >> 4, h = bh & 15;
  float v0 = V01[((size_t)(b*T_ + tt))*32 + h*2 + 0];
  float v1 = V01[((size_t)(b*T_ + tt))*32 + h*2 + 1];
  ph[idx] = atan2f(v0, v1 + 1e-8f);
}

__global__ void trig_kernel(const float* __restrict__ ph,
                            float* __restrict__ cosb, float* __restrict__ sinb)
{
  int idx = blockIdx.x*256 + threadIdx.x;
  float p = ph[idx];
  cosb[idx] = cosf(p);
  sinb[idx] = sinf(p);
}

// ---------------------------------------------------------------------------
// One Kuramoto step, flash-style: recompute QK^T per 64-row i-block, j-loop
// over all 2048 keys. Unnormalized softmax: C=sum e*cos_j, S=sum e*sin_j,
// E=sum e. coupling_i = (sin_i*C - cos_i*S)/E.  ph <- mod(ph+DT*(om+c), 2pi).
// Block: 4 waves, wave w owns i-rows [i0+16w, i0+16w+16), all j.
// ---------------------------------------------------------------------------
__global__ __launch_bounds__(256)
void osc_step(const unsigned short* __restrict__ Qb, const unsigned short* __restrict__ Kb,
              const float* __restrict__ cosb, const float* __restrict__ sinb,
              float* __restrict__ ph, const float* __restrict__ omega)
{
  const int bh = blockIdx.y;
  const int b = bh >> 4, h = bh & 15;
  const int i0 = blockIdx.x * 64;
  const int wv = threadIdx.x >> 6;
  const int lane = threadIdx.x & 63;
  const int lr = lane & 15, kg = lane >> 4;

  // Q fragments for this wave's 16 rows: k = kf*32 + kg*8 + e (pre-scaled by 1/8)
  const int qi = i0 + wv*16 + lr;
  const unsigned short* qrow = Qb + ((size_t)(b*T_ + qi))*D_ + h*DK_;
  s16x8 aq0 = *(const s16x8*)(qrow + kg*8);
  s16x8 aq1 = *(const s16x8*)(qrow + 32 + kg*8);

  const float* cosr = cosb + (size_t)bh*T_;
  const float* sinr = sinb + (size_t)bh*T_;
  const unsigned short* Kbase = Kb + ((size_t)(b*T_))*D_ + h*DK_;

  float Cacc[4] = {0.f,0.f,0.f,0.f};
  float Sacc[4] = {0.f,0.f,0.f,0.f};
  float Eacc[4] = {0.f,0.f,0.f,0.f};

  for (int j0 = 0; j0 < T_; j0 += 64) {
#pragma unroll
    for (int jf = 0; jf < 4; ++jf) {
      int jrow = j0 + jf*16 + lr;
      const unsigned short* krow = Kbase + (size_t)jrow*D_;
      s16x8 bk0 = *(const s16x8*)(krow + kg*8);
      s16x8 bk1 = *(const s16x8*)(krow + 32 + kg*8);
      f32x4 dd; dd[0]=0.f; dd[1]=0.f; dd[2]=0.f; dd[3]=0.f;
      dd = __builtin_amdgcn_mfma_f32_16x16x32_bf16(aq0, bk0, dd, 0, 0, 0);
      dd = __builtin_amdgcn_mfma_f32_16x16x32_bf16(aq1, bk1, dd, 0, 0, 0);
      float cj = cosr[jrow];   // col for this lane = jrow (lane&15 + 16*jf + j0)
      float sj = sinr[jrow];
#pragma unroll
      for (int r = 0; r < 4; ++r) {
        float e = expf(dd[r]);   // no max-sub needed: |logit| <= ~2.7
        Cacc[r] += e * cj;
        Sacc[r] += e * sj;
        Eacc[r] += e;
      }
    }
  }

  // reduce over the 16 j-lanes (lane bits 0-3); rows live on bits 4-5 + reg
#pragma unroll
  for (int m = 1; m < 16; m <<= 1) {
#pragma unroll
    for (int r = 0; r < 4; ++r) {
      Cacc[r] += __shfl_xor(Cacc[r], m);
      Sacc[r] += __shfl_xor(Sacc[r], m);
      Eacc[r] += __shfl_xor(Eacc[r], m);
    }
  }

  if (lr == 0) {
    float om = omega[h];
#pragma unroll
    for (int r = 0; r < 4; ++r) {
      int i = i0 + wv*16 + kg*4 + r;
      size_t pidx = (size_t)bh*T_ + i;
      float si = sinr[i], ci = cosr[i];
      float coupling = (si*Cacc[r] - ci*Sacc[r]) / Eacc[r];
      float pn = ph[pidx] + DT_*(om + coupling);
      pn = fmodf(pn, TWO_PI_F);
      if (pn < 0.f) pn += TWO_PI_F;   // match numpy mod semantics (sign of divisor)
      ph[pidx] = pn;
    }
  }
}

__global__ void vmod_kernel(float* __restrict__ V, const float* __restrict__ ph)
{
  int idx = blockIdx.x*256 + threadIdx.x;   // over M_*D_/4 float4s
  int row = idx >> 8;          // b*T + t
  int c4  = idx & 255;
  int h = c4 >> 4;             // (c4*4)/64
  int b = row >> 11, tt = row & 2047;
  float c = cosf(ph[((size_t)(b*H_ + h))*T_ + tt]);
  float4 v = ((float4*)V)[idx];
  v.x *= c; v.y *= c; v.z *= c; v.w *= c;
  ((float4*)V)[idx] = v;
}

// ---------------------------------------------------------------------------
extern "C" void kernel_launch(void* const* d_in, const int* in_sizes, int n_in,
                              void* d_out, int out_size, void* d_ws, size_t ws_size,
                              hipStream_t stream)
{
  const float* x     = (const float*)d_in[0];
  const float* Wq    = (const float*)d_in[1];
  const float* Wk    = (const float*)d_in[2];
  const float* Wv    = (const float*)d_in[3];
  const float* Wo    = (const float*)d_in[4];
  const float* omega = (const float*)d_in[5];
  float* out = (float*)d_out;

  // workspace carve (~35 MB)
  char* w = (char*)d_ws;
  unsigned short* Qb = (unsigned short*)w; w += (size_t)M_*D_*2;   // bf16, pre-scaled 1/8
  unsigned short* Kb = (unsigned short*)w; w += (size_t)M_*D_*2;   // bf16
  float* Vf   = (float*)w; w += (size_t)M_*D_*4;                   // f32 V (then v_mod in-place)
  float* ph   = (float*)w; w += (size_t)BH_*T_*4;
  float* cosb = (float*)w; w += (size_t)BH_*T_*4;
  float* sinb = (float*)w; w += (size_t)BH_*T_*4;
  float* V01  = (float*)w; w += (size_t)M_*32*4;

  dim3 gg(M_/128, 1024/128);
  gemm128<0><<<gg, 256, 0, stream>>>(x, Wq, (void*)Qb, nullptr, 0.125f);
  gemm128<0><<<gg, 256, 0, stream>>>(x, Wk, (void*)Kb, nullptr, 1.0f);
  gemm128<1><<<gg, 256, 0, stream>>>(x, Wv, (void*)Vf, nullptr, 1.0f);

  v01_kernel<<<M_/8, 256, 0, stream>>>(x, Wv, V01);
  phase_init<<<BH_*T_/256, 256, 0, stream>>>(V01, ph);

  for (int s = 0; s < NSTEP; ++s) {
    trig_kernel<<<BH_*T_/256, 256, 0, stream>>>(ph, cosb, sinb);
    osc_step<<<dim3(T_/64, BH_), 256, 0, stream>>>(Qb, Kb, cosb, sinb, ph, omega);
  }

  vmod_kernel<<<M_*D_/4/256, 256, 0, stream>>>(Vf, ph);
  gemm128<2><<<gg, 256, 0, stream>>>(Vf, Wo, (void*)out, x, 1.0f);
}

// Round 2
// 515.181 us; speedup vs baseline: 1.9240x; 1.9240x over previous
//
#include <hip/hip_runtime.h>
#include <hip/hip_bf16.h>

#define B_    2
#define T_    2048
#define D_    1024
#define H_    16
#define DK_   64
#define BH_   (B_*H_)
#define M_    (B_*T_)        // 4096 GEMM rows
#define NSTEP 5
#define DT_   0.1f
#define TWO_PI_F 6.28318530717958647692f

typedef __attribute__((ext_vector_type(8))) short s16x8;   // 8 bf16 (4 VGPRs)
typedef __attribute__((ext_vector_type(4))) float f32x4;
typedef __attribute__((ext_vector_type(2))) float f32x2;

__device__ __forceinline__ unsigned short f2bf(float f) {
  unsigned int u = __float_as_uint(f);
  u += 0x7FFFu + ((u >> 16) & 1u);       // round-to-nearest-even
  return (unsigned short)(u >> 16);
}

// ---------------------------------------------------------------------------
// GEMM: Y[m,n] = sum_k A[m,k] * W[n,k];  A: M_ x 1024 f32, W: 1024 x 1024 f32
// (both operands k-contiguous). MODE 0: store bf16(Y*scale). MODE 1: f32.
// MODE 2: f32(Y + res).  128x128 tile, 4 waves, 16x16x32 bf16 MFMA.
// ---------------------------------------------------------------------------
template<int MODE>
__global__ __launch_bounds__(256)
void gemm128(const float* __restrict__ A, const float* __restrict__ W,
             void* __restrict__ outp, const float* __restrict__ res, float scale)
{
  __shared__ short lA[128*32];
  __shared__ short lB[128*32];
  const int m0 = blockIdx.x * 128;
  const int n0 = blockIdx.y * 128;
  const int t  = threadIdx.x;
  const int wv = t >> 6;
  const int lane = t & 63;
  const int wm = wv >> 1, wn = wv & 1;
  const int lr = lane & 15, kg = lane >> 4;

  f32x4 acc[4][4];
#pragma unroll
  for (int i = 0; i < 4; ++i)
#pragma unroll
    for (int j = 0; j < 4; ++j) {
      acc[i][j][0] = 0.f; acc[i][j][1] = 0.f; acc[i][j][2] = 0.f; acc[i][j][3] = 0.f;
    }

  const int srow = t >> 2;    // 0..63
  const int sc   = t & 3;     // 16B chunk within 64B LDS row

  for (int kt = 0; kt < 1024; kt += 32) {
#pragma unroll
    for (int p = 0; p < 2; ++p) {
      int row = srow + p*64;
      int bo  = row*64 + ((sc*16) ^ ((row & 3) << 4));   // swizzled byte offset
      const float4* ga = (const float4*)(A + (size_t)(m0+row)*1024 + kt + sc*8);
      float4 a0 = ga[0], a1 = ga[1];
      s16x8 ha;
      ha[0]=(short)f2bf(a0.x); ha[1]=(short)f2bf(a0.y); ha[2]=(short)f2bf(a0.z); ha[3]=(short)f2bf(a0.w);
      ha[4]=(short)f2bf(a1.x); ha[5]=(short)f2bf(a1.y); ha[6]=(short)f2bf(a1.z); ha[7]=(short)f2bf(a1.w);
      *(s16x8*)((char*)lA + bo) = ha;
      const float4* gb = (const float4*)(W + (size_t)(n0+row)*1024 + kt + sc*8);
      float4 b0 = gb[0], b1 = gb[1];
      s16x8 hb;
      hb[0]=(short)f2bf(b0.x); hb[1]=(short)f2bf(b0.y); hb[2]=(short)f2bf(b0.z); hb[3]=(short)f2bf(b0.w);
      hb[4]=(short)f2bf(b1.x); hb[5]=(short)f2bf(b1.y); hb[6]=(short)f2bf(b1.z); hb[7]=(short)f2bf(b1.w);
      *(s16x8*)((char*)lB + bo) = hb;
    }
    __syncthreads();

    s16x8 af[4], bfr[4];
#pragma unroll
    for (int mf = 0; mf < 4; ++mf) {
      int row = wm*64 + mf*16 + lr;
      af[mf] = *(const s16x8*)((const char*)lA + row*64 + ((kg*16) ^ ((row & 3) << 4)));
    }
#pragma unroll
    for (int nf = 0; nf < 4; ++nf) {
      int row = wn*64 + nf*16 + lr;
      bfr[nf] = *(const s16x8*)((const char*)lB + row*64 + ((kg*16) ^ ((row & 3) << 4)));
    }
#pragma unroll
    for (int mf = 0; mf < 4; ++mf)
#pragma unroll
      for (int nf = 0; nf < 4; ++nf)
        acc[mf][nf] = __builtin_amdgcn_mfma_f32_16x16x32_bf16(af[mf], bfr[nf], acc[mf][nf], 0, 0, 0);
    __syncthreads();
  }

#pragma unroll
  for (int mf = 0; mf < 4; ++mf)
#pragma unroll
    for (int nf = 0; nf < 4; ++nf)
#pragma unroll
      for (int r = 0; r < 4; ++r) {
        int grow = m0 + wm*64 + mf*16 + kg*4 + r;   // C/D: row=(lane>>4)*4+reg
        int gcol = n0 + wn*64 + nf*16 + lr;         //      col=lane&15
        size_t o = (size_t)grow*1024 + gcol;
        float v = acc[mf][nf][r];
        if (MODE == 0)      ((unsigned short*)outp)[o] = f2bf(v*scale);
        else if (MODE == 1) ((float*)outp)[o] = v;
        else                ((float*)outp)[o] = v + res[o];
      }
}

// ---------------------------------------------------------------------------
// Exact f32 dot products for the 2 phase-relevant V columns per head.
// ---------------------------------------------------------------------------
__global__ __launch_bounds__(256)
void v01_kernel(const float* __restrict__ x, const float* __restrict__ Wv,
                float* __restrict__ V01)
{
  const int t = threadIdx.x;
  const int colid = t & 31;               // h = colid>>1, comp = colid&1
  const int row = blockIdx.x*8 + (t >> 5);
  const int wcol = (colid >> 1)*DK_ + (colid & 1);
  const float4* xr = (const float4*)(x  + (size_t)row*1024);
  const float4* wr = (const float4*)(Wv + (size_t)wcol*1024);
  float acc = 0.f;
  for (int k = 0; k < 256; ++k) {
    float4 a = xr[k], b = wr[k];
    acc += a.x*b.x + a.y*b.y + a.z*b.z + a.w*b.w;
  }
  V01[(size_t)row*32 + colid] = acc;
}

__global__ void phase_init(const float* __restrict__ V01, float* __restrict__ ph)
{
  int idx = blockIdx.x*256 + threadIdx.x;  // over B*H*T
  int tt = idx & (T_-1);
  int bh = idx >> 11;
  int b = bh >> 4, h = bh & 15;
  float v0 = V01[((size_t)(b*T_ + tt))*32 + h*2 + 0];
  float v1 = V01[((size_t)(b*T_ + tt))*32 + h*2 + 1];
  ph[idx] = atan2f(v0, v1 + 1e-8f);
}

__global__ void trig_kernel(const float* __restrict__ ph,
                            float* __restrict__ cosb, float* __restrict__ sinb)
{
  int idx = blockIdx.x*256 + threadIdx.x;
  float p = ph[idx];
  cosb[idx] = cosf(p);
  sinb[idx] = sinf(p);
}

// ---------------------------------------------------------------------------
// build_J: materialize unnormalized exp(q.k/8) as fp8 e4m3, row-contiguous.
// Grid (jchunk=2, iblk=32, bh=32); block 256 = 4 waves, wave w owns 16 i-rows.
// MFMA fragment layout -> LDS f32 tile -> pack fp8 -> coalesced uint4 store.
// ---------------------------------------------------------------------------
__global__ __launch_bounds__(256)
void build_J(const unsigned short* __restrict__ Qb, const unsigned short* __restrict__ Kb,
             unsigned char* __restrict__ J)
{
  const int jc  = blockIdx.x;
  const int i0  = blockIdx.y * 64;
  const int bh  = blockIdx.z;
  const int b = bh >> 4, h = bh & 15;
  const int wv = threadIdx.x >> 6;
  const int lane = threadIdx.x & 63;
  const int lr = lane & 15, kg = lane >> 4;

  __shared__ float tile[64][65];

  const int qi = i0 + wv*16 + lr;
  const unsigned short* qrow = Qb + ((size_t)(b*T_ + qi))*D_ + h*DK_;
  s16x8 aq0 = *(const s16x8*)(qrow + kg*8);
  s16x8 aq1 = *(const s16x8*)(qrow + 32 + kg*8);
  const unsigned short* Kbase = Kb + ((size_t)(b*T_))*D_ + h*DK_;

  const int prow = threadIdx.x >> 2;      // pack: 4 threads per row
  const int pq   = threadIdx.x & 3;
  unsigned char* Jrow = J + ((size_t)(bh*T_ + i0 + prow))*T_;

  for (int j0 = jc*1024; j0 < jc*1024 + 1024; j0 += 64) {
#pragma unroll
    for (int jf = 0; jf < 4; ++jf) {
      int jrow = j0 + jf*16 + lr;
      const unsigned short* krow = Kbase + (size_t)jrow*D_;
      s16x8 bk0 = *(const s16x8*)(krow + kg*8);
      s16x8 bk1 = *(const s16x8*)(krow + 32 + kg*8);
      f32x4 dd; dd[0]=0.f; dd[1]=0.f; dd[2]=0.f; dd[3]=0.f;
      dd = __builtin_amdgcn_mfma_f32_16x16x32_bf16(aq0, bk0, dd, 0, 0, 0);
      dd = __builtin_amdgcn_mfma_f32_16x16x32_bf16(aq1, bk1, dd, 0, 0, 0);
#pragma unroll
      for (int r = 0; r < 4; ++r)
        tile[wv*16 + kg*4 + r][jf*16 + lr] = __expf(dd[r]);
    }
    __syncthreads();
    {
      const float* tr = &tile[prow][pq*16];
      unsigned int d0 = 0, d1 = 0, d2 = 0, d3 = 0;
      d0 = __builtin_amdgcn_cvt_pk_fp8_f32(tr[0],  tr[1],  d0, false);
      d0 = __builtin_amdgcn_cvt_pk_fp8_f32(tr[2],  tr[3],  d0, true);
      d1 = __builtin_amdgcn_cvt_pk_fp8_f32(tr[4],  tr[5],  d1, false);
      d1 = __builtin_amdgcn_cvt_pk_fp8_f32(tr[6],  tr[7],  d1, true);
      d2 = __builtin_amdgcn_cvt_pk_fp8_f32(tr[8],  tr[9],  d2, false);
      d2 = __builtin_amdgcn_cvt_pk_fp8_f32(tr[10], tr[11], d2, true);
      d3 = __builtin_amdgcn_cvt_pk_fp8_f32(tr[12], tr[13], d3, false);
      d3 = __builtin_amdgcn_cvt_pk_fp8_f32(tr[14], tr[15], d3, true);
      uint4 pk; pk.x = d0; pk.y = d1; pk.z = d2; pk.w = d3;
      *(uint4*)(Jrow + j0 + pq*16) = pk;
    }
    __syncthreads();
  }
}

// ---------------------------------------------------------------------------
// j_step: streaming Kuramoto step.  Wave handles 4 consecutive rows (same bh);
// lane l covers j-dwords l+64k (4 fp8 each), cos/sin float4 loads amortized
// over the 4 rows.  C=sum s*cos, S=sum s*sin, E=sum s; coupling=(si*C-ci*S)/E.
// ---------------------------------------------------------------------------
__global__ __launch_bounds__(256)
void j_step(const unsigned char* __restrict__ J,
            const float* __restrict__ cosb, const float* __restrict__ sinb,
            float* __restrict__ ph, const float* __restrict__ omega)
{
  const int wv = threadIdx.x >> 6;
  const int lane = threadIdx.x & 63;
  const int r0 = (blockIdx.x*4 + wv)*4;      // first of 4 rows in [0, BH*T)
  const int bh = r0 >> 11;

  const unsigned int* Jr0 = (const unsigned int*)(J + (size_t)(r0+0)*T_);
  const unsigned int* Jr1 = (const unsigned int*)(J + (size_t)(r0+1)*T_);
  const unsigned int* Jr2 = (const unsigned int*)(J + (size_t)(r0+2)*T_);
  const unsigned int* Jr3 = (const unsigned int*)(J + (size_t)(r0+3)*T_);
  const float4* c4 = (const float4*)(cosb + (size_t)bh*T_);
  const float4* s4 = (const float4*)(sinb + (size_t)bh*T_);

  float C[4] = {0.f,0.f,0.f,0.f};
  float S[4] = {0.f,0.f,0.f,0.f};
  float E[4] = {0.f,0.f,0.f,0.f};

#pragma unroll
  for (int k = 0; k < 8; ++k) {
    int d = lane + k*64;
    float4 cj = c4[d];
    float4 sj = s4[d];
    unsigned int sv[4];
    sv[0] = Jr0[d]; sv[1] = Jr1[d]; sv[2] = Jr2[d]; sv[3] = Jr3[d];
#pragma unroll
    for (int row = 0; row < 4; ++row) {
      f32x2 lo = __builtin_amdgcn_cvt_pk_f32_fp8(sv[row], false);
      f32x2 hi = __builtin_amdgcn_cvt_pk_f32_fp8(sv[row], true);
      C[row] += lo[0]*cj.x + lo[1]*cj.y + hi[0]*cj.z + hi[1]*cj.w;
      S[row] += lo[0]*sj.x + lo[1]*sj.y + hi[0]*sj.z + hi[1]*sj.w;
      E[row] += (lo[0]+lo[1]) + (hi[0]+hi[1]);
    }
  }

#pragma unroll
  for (int m = 1; m < 64; m <<= 1) {
#pragma unroll
    for (int row = 0; row < 4; ++row) {
      C[row] += __shfl_xor(C[row], m);
      S[row] += __shfl_xor(S[row], m);
      E[row] += __shfl_xor(E[row], m);
    }
  }

  if (lane < 4) {
    int pidx = r0 + lane;
    float si = sinb[pidx], ci = cosb[pidx];
    float om = omega[bh & 15];
    float coupling = (si*C[lane] - ci*S[lane]) / E[lane];
    float pn = ph[pidx] + DT_*(om + coupling);
    pn = fmodf(pn, TWO_PI_F);
    if (pn < 0.f) pn += TWO_PI_F;
    ph[pidx] = pn;
  }
}

// ---------------------------------------------------------------------------
// Fallback (round-1) per-step recompute kernel — used only if ws too small.
// ---------------------------------------------------------------------------
__global__ __launch_bounds__(256)
void osc_step(const unsigned short* __restrict__ Qb, const unsigned short* __restrict__ Kb,
              const float* __restrict__ cosb, const float* __restrict__ sinb,
              float* __restrict__ ph, const float* __restrict__ omega)
{
  const int bh = blockIdx.y;
  const int b = bh >> 4, h = bh & 15;
  const int i0 = blockIdx.x * 64;
  const int wv = threadIdx.x >> 6;
  const int lane = threadIdx.x & 63;
  const int lr = lane & 15, kg = lane >> 4;

  const int qi = i0 + wv*16 + lr;
  const unsigned short* qrow = Qb + ((size_t)(b*T_ + qi))*D_ + h*DK_;
  s16x8 aq0 = *(const s16x8*)(qrow + kg*8);
  s16x8 aq1 = *(const s16x8*)(qrow + 32 + kg*8);

  const float* cosr = cosb + (size_t)bh*T_;
  const float* sinr = sinb + (size_t)bh*T_;
  const unsigned short* Kbase = Kb + ((size_t)(b*T_))*D_ + h*DK_;

  float Cacc[4] = {0.f,0.f,0.f,0.f};
  float Sacc[4] = {0.f,0.f,0.f,0.f};
  float Eacc[4] = {0.f,0.f,0.f,0.f};

  for (int j0 = 0; j0 < T_; j0 += 64) {
#pragma unroll
    for (int jf = 0; jf < 4; ++jf) {
      int jrow = j0 + jf*16 + lr;
      const unsigned short* krow = Kbase + (size_t)jrow*D_;
      s16x8 bk0 = *(const s16x8*)(krow + kg*8);
      s16x8 bk1 = *(const s16x8*)(krow + 32 + kg*8);
      f32x4 dd; dd[0]=0.f; dd[1]=0.f; dd[2]=0.f; dd[3]=0.f;
      dd = __builtin_amdgcn_mfma_f32_16x16x32_bf16(aq0, bk0, dd, 0, 0, 0);
      dd = __builtin_amdgcn_mfma_f32_16x16x32_bf16(aq1, bk1, dd, 0, 0, 0);
      float cj = cosr[jrow];
      float sj = sinr[jrow];
#pragma unroll
      for (int r = 0; r < 4; ++r) {
        float e = expf(dd[r]);
        Cacc[r] += e * cj;
        Sacc[r] += e * sj;
        Eacc[r] += e;
      }
    }
  }

#pragma unroll
  for (int m = 1; m < 16; m <<= 1) {
#pragma unroll
    for (int r = 0; r < 4; ++r) {
      Cacc[r] += __shfl_xor(Cacc[r], m);
      Sacc[r] += __shfl_xor(Sacc[r], m);
      Eacc[r] += __shfl_xor(Eacc[r], m);
    }
  }

  if (lr == 0) {
    float om = omega[h];
#pragma unroll
    for (int r = 0; r < 4; ++r) {
      int i = i0 + wv*16 + kg*4 + r;
      size_t pidx = (size_t)bh*T_ + i;
      float si = sinr[i], ci = cosr[i];
      float coupling = (si*Cacc[r] - ci*Sacc[r]) / Eacc[r];
      float pn = ph[pidx] + DT_*(om + coupling);
      pn = fmodf(pn, TWO_PI_F);
      if (pn < 0.f) pn += TWO_PI_F;
      ph[pidx] = pn;
    }
  }
}

__global__ void vmod_kernel(float* __restrict__ V, const float* __restrict__ ph)
{
  int idx = blockIdx.x*256 + threadIdx.x;   // over M_*D_/4 float4s
  int row = idx >> 8;          // b*T + t
  int c4  = idx & 255;
  int h = c4 >> 4;             // (c4*4)/64
  int b = row >> 11, tt = row & 2047;
  float c = cosf(ph[((size_t)(b*H_ + h))*T_ + tt]);
  float4 v = ((float4*)V)[idx];
  v.x *= c; v.y *= c; v.z *= c; v.w *= c;
  ((float4*)V)[idx] = v;
}

// ---------------------------------------------------------------------------
extern "C" void kernel_launch(void* const* d_in, const int* in_sizes, int n_in,
                              void* d_out, int out_size, void* d_ws, size_t ws_size,
                              hipStream_t stream)
{
  const float* x     = (const float*)d_in[0];
  const float* Wq    = (const float*)d_in[1];
  const float* Wk    = (const float*)d_in[2];
  const float* Wv    = (const float*)d_in[3];
  const float* Wo    = (const float*)d_in[4];
  const float* omega = (const float*)d_in[5];
  float* out = (float*)d_out;

  char* w = (char*)d_ws;
  unsigned short* Qb = (unsigned short*)w; w += (size_t)M_*D_*2;   // bf16, pre-scaled 1/8
  unsigned short* Kb = (unsigned short*)w; w += (size_t)M_*D_*2;   // bf16
  float* Vf   = (float*)w; w += (size_t)M_*D_*4;                   // f32 V
  float* ph   = (float*)w; w += (size_t)BH_*T_*4;
  float* cosb = (float*)w; w += (size_t)BH_*T_*4;
  float* sinb = (float*)w; w += (size_t)BH_*T_*4;
  float* V01  = (float*)w; w += (size_t)M_*32*4;
  unsigned char* J = (unsigned char*)w; w += (size_t)BH_*T_*T_;    // fp8, 128 MiB
  const size_t need = (size_t)(w - (char*)d_ws);
  const bool fast = (ws_size >= need);

  dim3 gg(M_/128, 1024/128);
  gemm128<0><<<gg, 256, 0, stream>>>(x, Wq, (void*)Qb, nullptr, 0.125f);
  gemm128<0><<<gg, 256, 0, stream>>>(x, Wk, (void*)Kb, nullptr, 1.0f);
  gemm128<1><<<gg, 256, 0, stream>>>(x, Wv, (void*)Vf, nullptr, 1.0f);

  v01_kernel<<<M_/8, 256, 0, stream>>>(x, Wv, V01);
  phase_init<<<BH_*T_/256, 256, 0, stream>>>(V01, ph);

  if (fast) {
    build_J<<<dim3(2, T_/64, BH_), 256, 0, stream>>>(Qb, Kb, J);
    for (int s = 0; s < NSTEP; ++s) {
      trig_kernel<<<BH_*T_/256, 256, 0, stream>>>(ph, cosb, sinb);
      j_step<<<BH_*T_/16, 256, 0, stream>>>(J, cosb, sinb, ph, omega);
    }
  } else {
    for (int s = 0; s < NSTEP; ++s) {
      trig_kernel<<<BH_*T_/256, 256, 0, stream>>>(ph, cosb, sinb);
      osc_step<<<dim3(T_/64, BH_), 256, 0, stream>>>(Qb, Kb, cosb, sinb, ph, omega);
    }
  }

  vmod_kernel<<<M_*D_/4/256, 256, 0, stream>>>(Vf, ph);
  gemm128<2><<<gg, 256, 0, stream>>>(Vf, Wo, (void*)out, x, 1.0f);
}

// Round 3
// 427.137 us; speedup vs baseline: 2.3206x; 1.2061x over previous
//
#include <hip/hip_runtime.h>
#include <hip/hip_bf16.h>

#define B_    2
#define T_    2048
#define D_    1024
#define H_    16
#define DK_   64
#define BH_   (B_*H_)
#define M_    (B_*T_)        // 4096 GEMM rows
#define NSTEP 5
#define DT_   0.1f
#define TWO_PI_F 6.28318530717958647692f

typedef __attribute__((ext_vector_type(8))) short s16x8;   // 8 bf16 (4 VGPRs)
typedef __attribute__((ext_vector_type(4))) float f32x4;
typedef __attribute__((ext_vector_type(2))) float f32x2;

__device__ __forceinline__ unsigned short f2bf(float f) {
  unsigned int u = __float_as_uint(f);
  u += 0x7FFFu + ((u >> 16) & 1u);       // round-to-nearest-even
  return (unsigned short)(u >> 16);
}

__device__ __forceinline__ void gload_lds16(const void* g, void* l) {
  __builtin_amdgcn_global_load_lds(
      (const __attribute__((address_space(1))) unsigned int*)g,
      (__attribute__((address_space(3))) unsigned int*)l, 16, 0, 0);
}

// ---------------------------------------------------------------------------
// f32 -> bf16 conversion (vectorized, one s16x8 per thread)
// ---------------------------------------------------------------------------
__device__ __forceinline__ void conv8(const float* in, unsigned short* out, int i) {
  const float4* p = (const float4*)in + (size_t)i*2;
  float4 a = p[0], b = p[1];
  s16x8 o;
  o[0]=(short)f2bf(a.x); o[1]=(short)f2bf(a.y); o[2]=(short)f2bf(a.z); o[3]=(short)f2bf(a.w);
  o[4]=(short)f2bf(b.x); o[5]=(short)f2bf(b.y); o[6]=(short)f2bf(b.z); o[7]=(short)f2bf(b.w);
  *(s16x8*)(out + (size_t)i*8) = o;
}

__global__ void conv_x(const float* __restrict__ in, unsigned short* __restrict__ out) {
  conv8(in, out, blockIdx.x*256 + threadIdx.x);
}

__global__ void conv_w(const float* __restrict__ wq, const float* __restrict__ wk,
                       const float* __restrict__ wv, const float* __restrict__ wo,
                       unsigned short* __restrict__ oq, unsigned short* __restrict__ ok,
                       unsigned short* __restrict__ ov, unsigned short* __restrict__ oo) {
  int y = blockIdx.y;
  const float* in = (y==0)?wq:(y==1)?wk:(y==2)?wv:wo;
  unsigned short* out = (y==0)?oq:(y==1)?ok:(y==2)?ov:oo;
  conv8(in, out, blockIdx.x*256 + threadIdx.x);
}

// ---------------------------------------------------------------------------
// bf16 GEMM, m97 structure: 128x128 tile, BK=64, 4 waves, global_load_lds(16B)
// with XOR-swizzled LDS (linear dest + inverse-swizzled global src, swizzled
// ds_read).  Y[m,n] = sum_k A[m,k]*W[n,k] (both k-contiguous).
// MODE 0: bf16(Y*scale).  MODE 2: f32(Y) + res.
// ---------------------------------------------------------------------------
template<int MODE>
__device__ __forceinline__ void gemm_body(const unsigned short* __restrict__ A,
    const unsigned short* __restrict__ W, void* __restrict__ outp,
    const float* __restrict__ res, float scale, int m0, int n0)
{
  __shared__ unsigned short lA[128*64];   // 16 KB each, rows of 64 bf16 (128B)
  __shared__ unsigned short lB[128*64];
  const int t = threadIdx.x, wv = t >> 6, lane = t & 63;
  const int wm = wv >> 1, wn = wv & 1;
  const int lr = lane & 15, kg = lane >> 4;
  const int lrow = lane >> 3, lch = lane & 7, sch = lch ^ lrow;  // src pre-swizzle

  f32x4 acc[4][4];
#pragma unroll
  for (int i = 0; i < 4; ++i)
#pragma unroll
    for (int j = 0; j < 4; ++j) { acc[i][j][0]=0.f; acc[i][j][1]=0.f; acc[i][j][2]=0.f; acc[i][j][3]=0.f; }

  for (int kt = 0; kt < 1024; kt += 64) {
#pragma unroll
    for (int ii = 0; ii < 4; ++ii) {
      const int inst = wv*4 + ii;               // 1KB chunk = 8 rows of 128B
      const int row  = inst*8 + lrow;
      gload_lds16(A + (size_t)(m0+row)*1024 + kt + sch*8, lA + inst*512);
      gload_lds16(W + (size_t)(n0+row)*1024 + kt + sch*8, lB + inst*512);
    }
    __syncthreads();

    s16x8 a0[4], a1[4], b0[4], b1[4];
#pragma unroll
    for (int mf = 0; mf < 4; ++mf) {
      int row = wm*64 + mf*16 + lr, s7 = row & 7;
      a0[mf] = *(const s16x8*)(lA + row*64 + ((kg^s7)*8));
      a1[mf] = *(const s16x8*)(lA + row*64 + (((kg+4)^s7)*8));
    }
#pragma unroll
    for (int nf = 0; nf < 4; ++nf) {
      int row = wn*64 + nf*16 + lr, s7 = row & 7;
      b0[nf] = *(const s16x8*)(lB + row*64 + ((kg^s7)*8));
      b1[nf] = *(const s16x8*)(lB + row*64 + (((kg+4)^s7)*8));
    }
#pragma unroll
    for (int mf = 0; mf < 4; ++mf)
#pragma unroll
      for (int nf = 0; nf < 4; ++nf) {
        acc[mf][nf] = __builtin_amdgcn_mfma_f32_16x16x32_bf16(a0[mf], b0[nf], acc[mf][nf], 0,0,0);
        acc[mf][nf] = __builtin_amdgcn_mfma_f32_16x16x32_bf16(a1[mf], b1[nf], acc[mf][nf], 0,0,0);
      }
    __syncthreads();
  }

#pragma unroll
  for (int mf = 0; mf < 4; ++mf)
#pragma unroll
    for (int nf = 0; nf < 4; ++nf)
#pragma unroll
      for (int r = 0; r < 4; ++r) {
        int grow = m0 + wm*64 + mf*16 + kg*4 + r;   // C/D: row=(lane>>4)*4+reg
        int gcol = n0 + wn*64 + nf*16 + lr;         //      col=lane&15
        size_t o = (size_t)grow*1024 + gcol;
        float v = acc[mf][nf][r];
        if (MODE == 0) ((unsigned short*)outp)[o] = f2bf(v*scale);
        else           ((float*)outp)[o] = v + res[o];
      }
}

__global__ __launch_bounds__(256)
void gemm_qkv(const unsigned short* __restrict__ xb,
              const unsigned short* __restrict__ wq, const unsigned short* __restrict__ wk,
              const unsigned short* __restrict__ wv_,
              unsigned short* __restrict__ Qb, unsigned short* __restrict__ Kb,
              unsigned short* __restrict__ Vb)
{
  const int z = blockIdx.z;
  const unsigned short* W = (z==0)?wq:((z==1)?wk:wv_);
  unsigned short* O = (z==0)?Qb:((z==1)?Kb:Vb);
  const float scale = (z==0) ? 0.125f : 1.0f;
  gemm_body<0>(xb, W, O, nullptr, scale, blockIdx.x*128, blockIdx.y*128);
}

__global__ __launch_bounds__(256)
void gemm_o(const unsigned short* __restrict__ Ab, const unsigned short* __restrict__ wo,
            float* __restrict__ out, const float* __restrict__ x)
{
  gemm_body<2>(Ab, wo, out, x, 1.0f, blockIdx.x*128, blockIdx.y*128);
}

// ---------------------------------------------------------------------------
// Exact f32 dot products for the 2 phase-relevant V columns per head.
// ---------------------------------------------------------------------------
__global__ __launch_bounds__(256)
void v01_kernel(const float* __restrict__ x, const float* __restrict__ Wv,
                float* __restrict__ V01)
{
  const int t = threadIdx.x;
  const int colid = t & 31;               // h = colid>>1, comp = colid&1
  const int row = blockIdx.x*8 + (t >> 5);
  const int wcol = (colid >> 1)*DK_ + (colid & 1);
  const float4* xr = (const float4*)(x  + (size_t)row*1024);
  const float4* wr = (const float4*)(Wv + (size_t)wcol*1024);
  float acc = 0.f;
  for (int k = 0; k < 256; ++k) {
    float4 a = xr[k], b = wr[k];
    acc += a.x*b.x + a.y*b.y + a.z*b.z + a.w*b.w;
  }
  V01[(size_t)row*32 + colid] = acc;
}

// phase init + cos/sin (cos(atan2(a,c)) = c/r, sin = a/r)
__global__ void phase_init2(const float* __restrict__ V01, float* __restrict__ ph,
                            float* __restrict__ cw, float* __restrict__ sw)
{
  int idx = blockIdx.x*256 + threadIdx.x;  // over B*H*T
  int tt = idx & (T_-1);
  int bh = idx >> 11;
  int b = bh >> 4, h = bh & 15;
  float a = V01[((size_t)(b*T_ + tt))*32 + h*2 + 0];
  float c = V01[((size_t)(b*T_ + tt))*32 + h*2 + 1] + 1e-8f;
  ph[idx] = atan2f(a, c);
  float r = fmaxf(sqrtf(a*a + c*c), 1e-30f);
  cw[idx] = c / r;
  sw[idx] = a / r;
}

// ---------------------------------------------------------------------------
// build_fast: J[i][j] = fp8(exp(q_i.k_j/8)), barrier-free & LDS-free.
// Swapped-operand MFMA: D = mfma(K_rows, Q_rows) -> lane (lr,kg) holds
// col i=lr, rows j=kg*4+0..3 (4 CONSECUTIVE j) -> pack 1 dword, store direct.
// Grid (2 j-chunks, T/64 i, BH), 4 waves (i-16 each), 8 waves/SIMD occupancy.
// ---------------------------------------------------------------------------
__global__ __launch_bounds__(256)
void build_fast(const unsigned short* __restrict__ Qb, const unsigned short* __restrict__ Kb,
                unsigned char* __restrict__ J)
{
  const int jc = blockIdx.x;
  const int i0 = blockIdx.y * 64;
  const int bh = blockIdx.z;
  const int b = bh >> 4, h = bh & 15;
  const int wv = threadIdx.x >> 6, lane = threadIdx.x & 63;
  const int lr = lane & 15, kg = lane >> 4;

  const int qi = i0 + wv*16 + lr;
  const unsigned short* qrow = Qb + ((size_t)(b*T_ + qi))*D_ + h*DK_;
  s16x8 bq0 = *(const s16x8*)(qrow + kg*8);          // B-frag: Q rows (i)
  s16x8 bq1 = *(const s16x8*)(qrow + 32 + kg*8);

  const unsigned short* Kbase = Kb + (size_t)b*T_*D_ + h*DK_;
  unsigned char* Jrow = J + ((size_t)(bh*T_) + qi)*T_;   // this lane's i-row

  const int jend = jc*1024 + 1024;
#pragma unroll 2
  for (int j0 = jc*1024; j0 < jend; j0 += 16) {
    const unsigned short* krow = Kbase + (size_t)(j0 + lr)*D_;
    s16x8 ak0 = *(const s16x8*)(krow + kg*8);        // A-frag: K rows (j)
    s16x8 ak1 = *(const s16x8*)(krow + 32 + kg*8);
    f32x4 dd; dd[0]=0.f; dd[1]=0.f; dd[2]=0.f; dd[3]=0.f;
    dd = __builtin_amdgcn_mfma_f32_16x16x32_bf16(ak0, bq0, dd, 0, 0, 0);
    dd = __builtin_amdgcn_mfma_f32_16x16x32_bf16(ak1, bq1, dd, 0, 0, 0);
    float e0 = __expf(dd[0]), e1 = __expf(dd[1]);
    float e2 = __expf(dd[2]), e3 = __expf(dd[3]);
    unsigned int pk = 0;
    pk = __builtin_amdgcn_cvt_pk_fp8_f32(e0, e1, pk, false);
    pk = __builtin_amdgcn_cvt_pk_fp8_f32(e2, e3, pk, true);
    *(unsigned int*)(Jrow + j0 + kg*4) = pk;         // j = j0 + kg*4 + 0..3
  }
}

// ---------------------------------------------------------------------------
// j_step2: streaming Kuramoto step (uint4 J loads, 4 rows/wave, cos/sin
// double-buffered; epilogue writes next step's cos/sin -> no trig kernel).
// ---------------------------------------------------------------------------
__global__ __launch_bounds__(256)
void j_step2(const unsigned char* __restrict__ J,
             const float* __restrict__ cr, const float* __restrict__ sr,
             float* __restrict__ cw, float* __restrict__ sw,
             float* __restrict__ ph, const float* __restrict__ omega)
{
  const int wv = threadIdx.x >> 6, lane = threadIdx.x & 63;
  const int r0 = (blockIdx.x*4 + wv)*4;      // 4 rows per wave, rows = bh*T+t
  const int bh = r0 >> 11;
  const float4* c4 = (const float4*)(cr + (size_t)bh*T_);
  const float4* s4 = (const float4*)(sr + (size_t)bh*T_);

  float C[4] = {0.f,0.f,0.f,0.f};
  float S[4] = {0.f,0.f,0.f,0.f};
  float E[4] = {0.f,0.f,0.f,0.f};

#pragma unroll
  for (int k = 0; k < 2; ++k) {
    int idx = k*64 + lane;                   // uint4 index (16 fp8 = 16 j)
    float4 cv[4], sv[4];
#pragma unroll
    for (int q = 0; q < 4; ++q) { cv[q] = c4[idx*4+q]; sv[q] = s4[idx*4+q]; }
#pragma unroll
    for (int row = 0; row < 4; ++row) {
      uint4 jv = *(const uint4*)(J + (size_t)(r0+row)*T_ + (size_t)idx*16);
      unsigned int wd0 = jv.x, wd1 = jv.y, wd2 = jv.z, wd3 = jv.w;
#pragma unroll
      for (int q = 0; q < 4; ++q) {
        unsigned int wq_ = (q==0)?wd0:(q==1)?wd1:(q==2)?wd2:wd3;
        f32x2 lo = __builtin_amdgcn_cvt_pk_f32_fp8(wq_, false);
        f32x2 hi = __builtin_amdgcn_cvt_pk_f32_fp8(wq_, true);
        C[row] += lo[0]*cv[q].x + lo[1]*cv[q].y + hi[0]*cv[q].z + hi[1]*cv[q].w;
        S[row] += lo[0]*sv[q].x + lo[1]*sv[q].y + hi[0]*sv[q].z + hi[1]*sv[q].w;
        E[row] += (lo[0]+lo[1]) + (hi[0]+hi[1]);
      }
    }
  }

#pragma unroll
  for (int m = 1; m < 64; m <<= 1) {
#pragma unroll
    for (int row = 0; row < 4; ++row) {
      C[row] += __shfl_xor(C[row], m);
      S[row] += __shfl_xor(S[row], m);
      E[row] += __shfl_xor(E[row], m);
    }
  }

  if (lane < 4) {
    float Cc = (lane==0)?C[0]:(lane==1)?C[1]:(lane==2)?C[2]:C[3];
    float Ss = (lane==0)?S[0]:(lane==1)?S[1]:(lane==2)?S[2]:S[3];
    float Ee = (lane==0)?E[0]:(lane==1)?E[1]:(lane==2)?E[2]:E[3];
    int pidx = r0 + lane;
    float si = sr[pidx], ci = cr[pidx];
    float om = omega[bh & 15];
    float coupling = (si*Cc - ci*Ss) / Ee;
    float pn = ph[pidx] + DT_*(om + coupling);
    pn = fmodf(pn, TWO_PI_F);
    if (pn < 0.f) pn += TWO_PI_F;            // numpy mod semantics
    ph[pidx] = pn;
    cw[pidx] = __cosf(pn);
    sw[pidx] = __sinf(pn);
  }
}

// vmod: V *= cos(phase_final) in bf16 (reads final cos buffer directly)
__global__ void vmod2(unsigned short* __restrict__ V, const float* __restrict__ cfin)
{
  int idx = blockIdx.x*256 + threadIdx.x;    // over M_*D_/8
  int row = idx >> 7;           // b*T + t
  int g = idx & 127;
  int h = g >> 3;               // 8 s16x8 groups per head
  int b = row >> 11, tt = row & 2047;
  float c = cfin[((size_t)(b*H_ + h))*T_ + tt];
  s16x8 v = *(s16x8*)(V + (size_t)idx*8);
  s16x8 o;
#pragma unroll
  for (int e = 0; e < 8; ++e) {
    float f = __uint_as_float(((unsigned int)(unsigned short)v[e]) << 16);
    o[e] = (short)f2bf(f * c);
  }
  *(s16x8*)(V + (size_t)idx*8) = o;
}

// ---------------------------------------------------------------------------
extern "C" void kernel_launch(void* const* d_in, const int* in_sizes, int n_in,
                              void* d_out, int out_size, void* d_ws, size_t ws_size,
                              hipStream_t stream)
{
  const float* x     = (const float*)d_in[0];
  const float* Wq    = (const float*)d_in[1];
  const float* Wk    = (const float*)d_in[2];
  const float* Wv    = (const float*)d_in[3];
  const float* Wo    = (const float*)d_in[4];
  const float* omega = (const float*)d_in[5];
  float* out = (float*)d_out;

  // workspace carve (~156 MiB; J aliases dead xb/wqb/wkb/wvb)
  char* w = (char*)d_ws;
  unsigned short* Qb  = (unsigned short*)w; w += (size_t)M_*D_*2;   // bf16, pre-scaled 1/8
  unsigned short* Kb  = (unsigned short*)w; w += (size_t)M_*D_*2;
  unsigned short* Vb  = (unsigned short*)w; w += (size_t)M_*D_*2;   // bf16 V (vmod in place)
  unsigned short* wob = (unsigned short*)w; w += (size_t)D_*D_*2;
  float* ph   = (float*)w; w += (size_t)BH_*T_*4;
  float* csb[2]; float* snb[2];
  csb[0] = (float*)w; w += (size_t)BH_*T_*4;
  snb[0] = (float*)w; w += (size_t)BH_*T_*4;
  csb[1] = (float*)w; w += (size_t)BH_*T_*4;
  snb[1] = (float*)w; w += (size_t)BH_*T_*4;
  float* V01 = (float*)w; w += (size_t)M_*32*4;
  unsigned char* J = (unsigned char*)w;                             // 128 MiB
  // aliased into J's head (dead once build_fast runs):
  unsigned short* xb  = (unsigned short*)J;                         // 8 MiB
  unsigned short* wqb = (unsigned short*)(J + (size_t)M_*D_*2);
  unsigned short* wkb = wqb + (size_t)D_*D_;
  unsigned short* wvb = wkb + (size_t)D_*D_;

  conv_x<<<M_*D_/8/256, 256, 0, stream>>>(x, xb);
  conv_w<<<dim3(D_*D_/8/256, 4), 256, 0, stream>>>(Wq, Wk, Wv, Wo, wqb, wkb, wvb, wob);

  gemm_qkv<<<dim3(M_/128, D_/128, 3), 256, 0, stream>>>(xb, wqb, wkb, wvb, Qb, Kb, Vb);

  v01_kernel<<<M_/8, 256, 0, stream>>>(x, Wv, V01);
  phase_init2<<<BH_*T_/256, 256, 0, stream>>>(V01, ph, csb[0], snb[0]);

  build_fast<<<dim3(2, T_/64, BH_), 256, 0, stream>>>(Qb, Kb, J);   // overwrites xb/wqkv

  for (int s = 0; s < NSTEP; ++s)
    j_step2<<<BH_*T_/16, 256, 0, stream>>>(J, csb[s&1], snb[s&1],
                                           csb[(s+1)&1], snb[(s+1)&1], ph, omega);

  vmod2<<<M_*D_/8/256, 256, 0, stream>>>(Vb, csb[NSTEP&1]);
  gemm_o<<<dim3(M_/128, D_/128), 256, 0, stream>>>(Vb, wob, out, x);
}

// Round 4
// 368.891 us; speedup vs baseline: 2.6870x; 1.1579x over previous
//
#include <hip/hip_runtime.h>
#include <hip/hip_bf16.h>

#define B_    2
#define T_    2048
#define D_    1024
#define H_    16
#define DK_   64
#define BH_   (B_*H_)
#define M_    (B_*T_)        // 4096 GEMM rows
#define NSTEP 5
#define DT_   0.1f
#define TWO_PI_F 6.28318530717958647692f

typedef __attribute__((ext_vector_type(8))) short s16x8;   // 8 bf16 (4 VGPRs)
typedef __attribute__((ext_vector_type(4))) float f32x4;
typedef __attribute__((ext_vector_type(2))) float f32x2;

__device__ __forceinline__ unsigned short f2bf(float f) {
  unsigned int u = __float_as_uint(f);
  u += 0x7FFFu + ((u >> 16) & 1u);       // round-to-nearest-even
  return (unsigned short)(u >> 16);
}

__device__ __forceinline__ void gload_lds16(const void* g, void* l) {
  __builtin_amdgcn_global_load_lds(
      (const __attribute__((address_space(1))) unsigned int*)g,
      (__attribute__((address_space(3))) unsigned int*)l, 16, 0, 0);
}

// ---------------------------------------------------------------------------
// f32 -> bf16 conversion, all 5 tensors in one launch.
// ---------------------------------------------------------------------------
__device__ __forceinline__ void conv8(const float* in, unsigned short* out, int i) {
  const float4* p = (const float4*)in + (size_t)i*2;
  float4 a = p[0], b = p[1];
  s16x8 o;
  o[0]=(short)f2bf(a.x); o[1]=(short)f2bf(a.y); o[2]=(short)f2bf(a.z); o[3]=(short)f2bf(a.w);
  o[4]=(short)f2bf(b.x); o[5]=(short)f2bf(b.y); o[6]=(short)f2bf(b.z); o[7]=(short)f2bf(b.w);
  *(s16x8*)(out + (size_t)i*8) = o;
}

__global__ void conv_all(const float* __restrict__ x,
                         const float* __restrict__ wq, const float* __restrict__ wk,
                         const float* __restrict__ wv, const float* __restrict__ wo,
                         unsigned short* __restrict__ xb,
                         unsigned short* __restrict__ oq, unsigned short* __restrict__ ok,
                         unsigned short* __restrict__ ov, unsigned short* __restrict__ oo)
{
  int bid = blockIdx.x;
  if (bid < 2048) {                       // x: 4M elements
    conv8(x, xb, bid*256 + threadIdx.x);
  } else {                                // weights: 1M each, 512 blocks each
    int r = bid - 2048;
    int z = r >> 9, lb = r & 511;
    const float* in = (z==0)?wq:(z==1)?wk:(z==2)?wv:wo;
    unsigned short* out = (z==0)?oq:(z==1)?ok:(z==2)?ov:oo;
    conv8(in, out, lb*256 + threadIdx.x);
  }
}

// ---------------------------------------------------------------------------
// bf16 GEMM (m97 structure): BMx128 tile, BK=64, 4 waves, global_load_lds(16B),
// XOR-swizzled LDS (linear dest + pre-swizzled global src + swizzled ds_read).
// Y[m,n] = sum_k A[m,k]*W[n,k].  MODE 0: bf16(Y*scale). MODE 2: f32(Y)+res.
// ---------------------------------------------------------------------------
template<int BM, int MODE>
__device__ __forceinline__ void gemm_body(const unsigned short* __restrict__ A,
    const unsigned short* __restrict__ W, void* __restrict__ outp,
    const float* __restrict__ res, float scale, int m0, int n0)
{
  constexpr int MF = BM/32;               // fragment rows per wave
  __shared__ unsigned short lA[BM*64];
  __shared__ unsigned short lB[128*64];
  const int t = threadIdx.x, wv = t >> 6, lane = t & 63;
  const int wm = wv >> 1, wn = wv & 1;
  const int lr = lane & 15, kg = lane >> 4;
  const int lrow = lane >> 3, sch = (lane & 7) ^ lrow;   // src pre-swizzle

  f32x4 acc[MF][4];
#pragma unroll
  for (int i = 0; i < MF; ++i)
#pragma unroll
    for (int j = 0; j < 4; ++j) { acc[i][j][0]=0.f; acc[i][j][1]=0.f; acc[i][j][2]=0.f; acc[i][j][3]=0.f; }

  for (int kt = 0; kt < 1024; kt += 64) {
#pragma unroll
    for (int ii = 0; ii < BM/32; ++ii) {
      const int inst = wv*(BM/32) + ii;
      const int row  = inst*8 + lrow;
      gload_lds16(A + (size_t)(m0+row)*1024 + kt + sch*8, lA + inst*512);
    }
#pragma unroll
    for (int ii = 0; ii < 4; ++ii) {
      const int inst = wv*4 + ii;
      const int row  = inst*8 + lrow;
      gload_lds16(W + (size_t)(n0+row)*1024 + kt + sch*8, lB + inst*512);
    }
    __syncthreads();

    s16x8 a0[MF], a1[MF], b0[4], b1[4];
#pragma unroll
    for (int mf = 0; mf < MF; ++mf) {
      int row = wm*(BM/2) + mf*16 + lr, s7 = row & 7;
      a0[mf] = *(const s16x8*)(lA + row*64 + ((kg^s7)*8));
      a1[mf] = *(const s16x8*)(lA + row*64 + (((kg+4)^s7)*8));
    }
#pragma unroll
    for (int nf = 0; nf < 4; ++nf) {
      int row = wn*64 + nf*16 + lr, s7 = row & 7;
      b0[nf] = *(const s16x8*)(lB + row*64 + ((kg^s7)*8));
      b1[nf] = *(const s16x8*)(lB + row*64 + (((kg+4)^s7)*8));
    }
#pragma unroll
    for (int mf = 0; mf < MF; ++mf)
#pragma unroll
      for (int nf = 0; nf < 4; ++nf) {
        acc[mf][nf] = __builtin_amdgcn_mfma_f32_16x16x32_bf16(a0[mf], b0[nf], acc[mf][nf], 0,0,0);
        acc[mf][nf] = __builtin_amdgcn_mfma_f32_16x16x32_bf16(a1[mf], b1[nf], acc[mf][nf], 0,0,0);
      }
    __syncthreads();
  }

#pragma unroll
  for (int mf = 0; mf < MF; ++mf)
#pragma unroll
    for (int nf = 0; nf < 4; ++nf)
#pragma unroll
      for (int r = 0; r < 4; ++r) {
        int grow = m0 + wm*(BM/2) + mf*16 + kg*4 + r;   // C/D: row=(lane>>4)*4+reg
        int gcol = n0 + wn*64 + nf*16 + lr;             //      col=lane&15
        size_t o = (size_t)grow*1024 + gcol;
        float v = acc[mf][nf][r];
        if (MODE == 0) ((unsigned short*)outp)[o] = f2bf(v*scale);
        else           ((float*)outp)[o] = v + res[o];
      }
}

__global__ __launch_bounds__(256)
void gemm_qkv(const unsigned short* __restrict__ xb,
              const unsigned short* __restrict__ wq, const unsigned short* __restrict__ wk,
              const unsigned short* __restrict__ wv_,
              unsigned short* __restrict__ Qb, unsigned short* __restrict__ Kb,
              unsigned short* __restrict__ Vb)
{
  const int z = blockIdx.z;
  const unsigned short* W = (z==0)?wq:((z==1)?wk:wv_);
  unsigned short* O = (z==0)?Qb:((z==1)?Kb:Vb);
  const float scale = (z==0) ? 0.125f : 1.0f;
  gemm_body<128,0>(xb, W, O, nullptr, scale, blockIdx.x*128, blockIdx.y*128);
}

__global__ __launch_bounds__(256)
void gemm_o(const unsigned short* __restrict__ Ab, const unsigned short* __restrict__ wo,
            float* __restrict__ out, const float* __restrict__ x)
{
  gemm_body<64,2>(Ab, wo, out, x, 1.0f, blockIdx.x*64, blockIdx.y*128);
}

// ---------------------------------------------------------------------------
// Exact f32 dot products for the 2 phase-relevant V columns per head.
// ---------------------------------------------------------------------------
__global__ __launch_bounds__(256)
void v01_kernel(const float* __restrict__ x, const float* __restrict__ Wv,
                float* __restrict__ V01)
{
  const int t = threadIdx.x;
  const int colid = t & 31;               // h = colid>>1, comp = colid&1
  const int row = blockIdx.x*8 + (t >> 5);
  const int wcol = (colid >> 1)*DK_ + (colid & 1);
  const float4* xr = (const float4*)(x  + (size_t)row*1024);
  const float4* wr = (const float4*)(Wv + (size_t)wcol*1024);
  float acc = 0.f;
  for (int k = 0; k < 256; ++k) {
    float4 a = xr[k], b = wr[k];
    acc += a.x*b.x + a.y*b.y + a.z*b.z + a.w*b.w;
  }
  V01[(size_t)row*32 + colid] = acc;
}

// phase init + exact cos/sin (cos(atan2(a,c)) = c/r, sin = a/r)
__global__ void phase_init2(const float* __restrict__ V01, float* __restrict__ ph,
                            float* __restrict__ cw, float* __restrict__ sw)
{
  int idx = blockIdx.x*256 + threadIdx.x;  // over B*H*T
  int tt = idx & (T_-1);
  int bh = idx >> 11;
  int b = bh >> 4, h = bh & 15;
  float a = V01[((size_t)(b*T_ + tt))*32 + h*2 + 0];
  float c = V01[((size_t)(b*T_ + tt))*32 + h*2 + 1] + 1e-8f;
  ph[idx] = atan2f(a, c);
  float r = fmaxf(sqrtf(a*a + c*c), 1e-30f);
  cw[idx] = c / r;
  sw[idx] = a / r;
}

// ---------------------------------------------------------------------------
// build_step1: J[i][j] = fp8(exp(q_i.k_j/8)) AND oscillator step 1, fused.
// Swapped-operand MFMA (verified r3): mfma(K_j, Q_i) -> lane(lr,kg) holds
// col i=lr, rows j=kg*4+r.  Each wave holds Q-frags for 4 i-tiles (64 i) and
// reuses every K-fragment 4x (8 MFMA + 16 exp per iter -> ILP hides latency).
// Block = 4 waves x 512-j strips = full j range -> C/S/E complete per block;
// epilogue updates ph and writes step-1 cos/sin. Grid (T/64, BH).
// ---------------------------------------------------------------------------
__global__ __launch_bounds__(256, 4)
void build_step1(const unsigned short* __restrict__ Qb, const unsigned short* __restrict__ Kb,
                 unsigned char* __restrict__ J,
                 const float* __restrict__ cr, const float* __restrict__ sr,
                 float* __restrict__ cw, float* __restrict__ sw,
                 float* __restrict__ ph, const float* __restrict__ omega)
{
  const int i0 = blockIdx.x * 64;
  const int bh = blockIdx.y;
  const int b = bh >> 4, h = bh & 15;
  const int wv = threadIdx.x >> 6, lane = threadIdx.x & 63;
  const int lr = lane & 15, kg = lane >> 4;

  __shared__ float red[4][3][64];

  s16x8 bq0[4], bq1[4];
#pragma unroll
  for (int it = 0; it < 4; ++it) {
    const unsigned short* qrow = Qb + ((size_t)(b*T_ + i0 + it*16 + lr))*D_ + h*DK_;
    bq0[it] = *(const s16x8*)(qrow + kg*8);
    bq1[it] = *(const s16x8*)(qrow + 32 + kg*8);
  }
  const unsigned short* Kbase = Kb + (size_t)b*T_*D_ + h*DK_;
  const float* crow = cr + (size_t)bh*T_;
  const float* srow = sr + (size_t)bh*T_;
  unsigned char* Jb = J + ((size_t)(bh*T_ + i0))*T_;

  float Cp[4] = {0.f,0.f,0.f,0.f};
  float Sp[4] = {0.f,0.f,0.f,0.f};
  float Ep[4] = {0.f,0.f,0.f,0.f};

  const int jbase = wv * 512;
  for (int jt = 0; jt < 512; jt += 16) {
    const int j0 = jbase + jt;
    const unsigned short* krow = Kbase + (size_t)(j0 + lr)*D_;
    s16x8 ak0 = *(const s16x8*)(krow + kg*8);
    s16x8 ak1 = *(const s16x8*)(krow + 32 + kg*8);
    float4 cj = *(const float4*)(crow + j0 + kg*4);
    float4 sj = *(const float4*)(srow + j0 + kg*4);
#pragma unroll
    for (int it = 0; it < 4; ++it) {
      f32x4 dd; dd[0]=0.f; dd[1]=0.f; dd[2]=0.f; dd[3]=0.f;
      dd = __builtin_amdgcn_mfma_f32_16x16x32_bf16(ak0, bq0[it], dd, 0, 0, 0);
      dd = __builtin_amdgcn_mfma_f32_16x16x32_bf16(ak1, bq1[it], dd, 0, 0, 0);
      float e0 = __expf(dd[0]), e1 = __expf(dd[1]);
      float e2 = __expf(dd[2]), e3 = __expf(dd[3]);
      unsigned int pk = 0;
      pk = __builtin_amdgcn_cvt_pk_fp8_f32(e0, e1, pk, false);
      pk = __builtin_amdgcn_cvt_pk_fp8_f32(e2, e3, pk, true);
      *(unsigned int*)(Jb + (size_t)(it*16 + lr)*T_ + j0 + kg*4) = pk;
      Cp[it] += e0*cj.x + e1*cj.y + e2*cj.z + e3*cj.w;
      Sp[it] += e0*sj.x + e1*sj.y + e2*sj.z + e3*sj.w;
      Ep[it] += e0 + e1 + e2 + e3;
    }
  }

  // reduce over kg (lane bits 4,5): all j covered
#pragma unroll
  for (int m = 16; m < 64; m <<= 1)
#pragma unroll
    for (int it = 0; it < 4; ++it) {
      Cp[it] += __shfl_xor(Cp[it], m);
      Sp[it] += __shfl_xor(Sp[it], m);
      Ep[it] += __shfl_xor(Ep[it], m);
    }
  if (kg == 0) {
#pragma unroll
    for (int it = 0; it < 4; ++it) {
      red[wv][0][it*16 + lr] = Cp[it];
      red[wv][1][it*16 + lr] = Sp[it];
      red[wv][2][it*16 + lr] = Ep[it];
    }
  }
  __syncthreads();
  if (threadIdx.x < 64) {
    int i = threadIdx.x;
    float C = red[0][0][i] + red[1][0][i] + red[2][0][i] + red[3][0][i];
    float S = red[0][1][i] + red[1][1][i] + red[2][1][i] + red[3][1][i];
    float E = red[0][2][i] + red[1][2][i] + red[2][2][i] + red[3][2][i];
    size_t pidx = (size_t)bh*T_ + i0 + i;
    float si = srow[i0 + i], ci = crow[i0 + i];
    float coupling = (si*C - ci*S) / E;
    float pn = ph[pidx] + DT_*(omega[h] + coupling);
    pn = fmodf(pn, TWO_PI_F);
    if (pn < 0.f) pn += TWO_PI_F;            // numpy mod semantics
    ph[pidx] = pn;
    cw[pidx] = __cosf(pn);
    sw[pidx] = __sinf(pn);
  }
}

// ---------------------------------------------------------------------------
// j_step2: streaming Kuramoto step (uint4 J loads, 4 rows/wave, cos/sin
// double-buffered; epilogue writes next step's cos/sin).
// ---------------------------------------------------------------------------
__global__ __launch_bounds__(256)
void j_step2(const unsigned char* __restrict__ J,
             const float* __restrict__ cr, const float* __restrict__ sr,
             float* __restrict__ cw, float* __restrict__ sw,
             float* __restrict__ ph, const float* __restrict__ omega)
{
  const int wv = threadIdx.x >> 6, lane = threadIdx.x & 63;
  const int r0 = (blockIdx.x*4 + wv)*4;      // 4 rows per wave, rows = bh*T+t
  const int bh = r0 >> 11;
  const float4* c4 = (const float4*)(cr + (size_t)bh*T_);
  const float4* s4 = (const float4*)(sr + (size_t)bh*T_);

  float C[4] = {0.f,0.f,0.f,0.f};
  float S[4] = {0.f,0.f,0.f,0.f};
  float E[4] = {0.f,0.f,0.f,0.f};

#pragma unroll
  for (int k = 0; k < 2; ++k) {
    int idx = k*64 + lane;                   // uint4 index (16 fp8 = 16 j)
    float4 cv[4], sv[4];
#pragma unroll
    for (int q = 0; q < 4; ++q) { cv[q] = c4[idx*4+q]; sv[q] = s4[idx*4+q]; }
#pragma unroll
    for (int row = 0; row < 4; ++row) {
      uint4 jv = *(const uint4*)(J + (size_t)(r0+row)*T_ + (size_t)idx*16);
#pragma unroll
      for (int q = 0; q < 4; ++q) {
        unsigned int wq_ = (q==0)?jv.x:(q==1)?jv.y:(q==2)?jv.z:jv.w;
        f32x2 lo = __builtin_amdgcn_cvt_pk_f32_fp8(wq_, false);
        f32x2 hi = __builtin_amdgcn_cvt_pk_f32_fp8(wq_, true);
        C[row] += lo[0]*cv[q].x + lo[1]*cv[q].y + hi[0]*cv[q].z + hi[1]*cv[q].w;
        S[row] += lo[0]*sv[q].x + lo[1]*sv[q].y + hi[0]*sv[q].z + hi[1]*sv[q].w;
        E[row] += (lo[0]+lo[1]) + (hi[0]+hi[1]);
      }
    }
  }

#pragma unroll
  for (int m = 1; m < 64; m <<= 1) {
#pragma unroll
    for (int row = 0; row < 4; ++row) {
      C[row] += __shfl_xor(C[row], m);
      S[row] += __shfl_xor(S[row], m);
      E[row] += __shfl_xor(E[row], m);
    }
  }

  if (lane < 4) {
    float Cc = (lane==0)?C[0]:(lane==1)?C[1]:(lane==2)?C[2]:C[3];
    float Ss = (lane==0)?S[0]:(lane==1)?S[1]:(lane==2)?S[2]:S[3];
    float Ee = (lane==0)?E[0]:(lane==1)?E[1]:(lane==2)?E[2]:E[3];
    int pidx = r0 + lane;
    float si = sr[pidx], ci = cr[pidx];
    float om = omega[bh & 15];
    float coupling = (si*Cc - ci*Ss) / Ee;
    float pn = ph[pidx] + DT_*(om + coupling);
    pn = fmodf(pn, TWO_PI_F);
    if (pn < 0.f) pn += TWO_PI_F;
    ph[pidx] = pn;
    cw[pidx] = __cosf(pn);
    sw[pidx] = __sinf(pn);
  }
}

// vmod: V *= cos(phase_final) in bf16 (reads final cos buffer)
__global__ void vmod2(unsigned short* __restrict__ V, const float* __restrict__ cfin)
{
  int idx = blockIdx.x*256 + threadIdx.x;    // over M_*D_/8
  int row = idx >> 7;           // b*T + t
  int g = idx & 127;
  int h = g >> 3;               // 8 s16x8 groups per head
  int b = row >> 11, tt = row & 2047;
  float c = cfin[((size_t)(b*H_ + h))*T_ + tt];
  s16x8 v = *(s16x8*)(V + (size_t)idx*8);
  s16x8 o;
#pragma unroll
  for (int e = 0; e < 8; ++e) {
    float f = __uint_as_float(((unsigned int)(unsigned short)v[e]) << 16);
    o[e] = (short)f2bf(f * c);
  }
  *(s16x8*)(V + (size_t)idx*8) = o;
}

// ---------------------------------------------------------------------------
extern "C" void kernel_launch(void* const* d_in, const int* in_sizes, int n_in,
                              void* d_out, int out_size, void* d_ws, size_t ws_size,
                              hipStream_t stream)
{
  const float* x     = (const float*)d_in[0];
  const float* Wq    = (const float*)d_in[1];
  const float* Wk    = (const float*)d_in[2];
  const float* Wv    = (const float*)d_in[3];
  const float* Wo    = (const float*)d_in[4];
  const float* omega = (const float*)d_in[5];
  float* out = (float*)d_out;

  // workspace carve (~156 MiB; J aliases dead xb/wqb/wkb/wvb)
  char* w = (char*)d_ws;
  unsigned short* Qb  = (unsigned short*)w; w += (size_t)M_*D_*2;   // bf16, pre-scaled 1/8
  unsigned short* Kb  = (unsigned short*)w; w += (size_t)M_*D_*2;
  unsigned short* Vb  = (unsigned short*)w; w += (size_t)M_*D_*2;   // bf16 V (vmod in place)
  unsigned short* wob = (unsigned short*)w; w += (size_t)D_*D_*2;
  float* ph   = (float*)w; w += (size_t)BH_*T_*4;
  float* csb[2]; float* snb[2];
  csb[0] = (float*)w; w += (size_t)BH_*T_*4;
  snb[0] = (float*)w; w += (size_t)BH_*T_*4;
  csb[1] = (float*)w; w += (size_t)BH_*T_*4;
  snb[1] = (float*)w; w += (size_t)BH_*T_*4;
  float* V01 = (float*)w; w += (size_t)M_*32*4;
  unsigned char* J = (unsigned char*)w;                             // 128 MiB
  // aliased into J's head (dead once build_step1 runs):
  unsigned short* xb  = (unsigned short*)J;                         // 8 MiB
  unsigned short* wqb = (unsigned short*)(J + (size_t)M_*D_*2);
  unsigned short* wkb = wqb + (size_t)D_*D_;
  unsigned short* wvb = wkb + (size_t)D_*D_;

  conv_all<<<4096, 256, 0, stream>>>(x, Wq, Wk, Wv, Wo, xb, wqb, wkb, wvb, wob);

  gemm_qkv<<<dim3(M_/128, D_/128, 3), 256, 0, stream>>>(xb, wqb, wkb, wvb, Qb, Kb, Vb);

  v01_kernel<<<M_/8, 256, 0, stream>>>(x, Wv, V01);
  phase_init2<<<BH_*T_/256, 256, 0, stream>>>(V01, ph, csb[0], snb[0]);

  // step 1 fused with J materialization (overwrites xb/wq/wk/wv alias region)
  build_step1<<<dim3(T_/64, BH_), 256, 0, stream>>>(Qb, Kb, J, csb[0], snb[0],
                                                    csb[1], snb[1], ph, omega);

  for (int s = 1; s < NSTEP; ++s)
    j_step2<<<BH_*T_/16, 256, 0, stream>>>(J, csb[s&1], snb[s&1],
                                           csb[(s+1)&1], snb[(s+1)&1], ph, omega);

  vmod2<<<M_*D_/8/256, 256, 0, stream>>>(Vb, csb[NSTEP&1]);
  gemm_o<<<dim3(M_/64, D_/128), 256, 0, stream>>>(Vb, wob, out, x);
}

// Round 5
// 357.648 us; speedup vs baseline: 2.7715x; 1.0314x over previous
//
#include <hip/hip_runtime.h>
#include <hip/hip_bf16.h>

#define B_    2
#define T_    2048
#define D_    1024
#define H_    16
#define DK_   64
#define BH_   (B_*H_)
#define M_    (B_*T_)        // 4096 GEMM rows
#define NSTEP 5
#define DT_   0.1f
#define TWO_PI_F 6.28318530717958647692f

typedef __attribute__((ext_vector_type(8))) short s16x8;   // 8 bf16 (4 VGPRs)
typedef __attribute__((ext_vector_type(4))) float f32x4;
typedef __attribute__((ext_vector_type(2))) float f32x2;

__device__ __forceinline__ unsigned short f2bf(float f) {
  unsigned int u = __float_as_uint(f);
  u += 0x7FFFu + ((u >> 16) & 1u);       // round-to-nearest-even
  return (unsigned short)(u >> 16);
}

__device__ __forceinline__ void gload_lds16(const void* g, void* l) {
  __builtin_amdgcn_global_load_lds(
      (const __attribute__((address_space(1))) unsigned int*)g,
      (__attribute__((address_space(3))) unsigned int*)l, 16, 0, 0);
}

// ---------------------------------------------------------------------------
// f32 -> bf16 conversion, all 5 tensors in one launch.
// ---------------------------------------------------------------------------
__device__ __forceinline__ void conv8(const float* in, unsigned short* out, int i) {
  const float4* p = (const float4*)in + (size_t)i*2;
  float4 a = p[0], b = p[1];
  s16x8 o;
  o[0]=(short)f2bf(a.x); o[1]=(short)f2bf(a.y); o[2]=(short)f2bf(a.z); o[3]=(short)f2bf(a.w);
  o[4]=(short)f2bf(b.x); o[5]=(short)f2bf(b.y); o[6]=(short)f2bf(b.z); o[7]=(short)f2bf(b.w);
  *(s16x8*)(out + (size_t)i*8) = o;
}

__global__ void conv_all(const float* __restrict__ x,
                         const float* __restrict__ wq, const float* __restrict__ wk,
                         const float* __restrict__ wv, const float* __restrict__ wo,
                         unsigned short* __restrict__ xb,
                         unsigned short* __restrict__ oq, unsigned short* __restrict__ ok,
                         unsigned short* __restrict__ ov, unsigned short* __restrict__ oo)
{
  int bid = blockIdx.x;
  if (bid < 2048) {                       // x: 4M elements
    conv8(x, xb, bid*256 + threadIdx.x);
  } else {                                // weights: 1M each, 512 blocks each
    int r = bid - 2048;
    int z = r >> 9, lb = r & 511;
    const float* in = (z==0)?wq:(z==1)?wk:(z==2)?wv:wo;
    unsigned short* out = (z==0)?oq:(z==1)?ok:(z==2)?ov:oo;
    conv8(in, out, lb*256 + threadIdx.x);
  }
}

// ---------------------------------------------------------------------------
// bf16 GEMM (m97 structure): BMx128 tile, BK=64, 4 waves, global_load_lds(16B),
// XOR-swizzled LDS (linear dest + pre-swizzled global src + swizzled ds_read).
// Y[m,n] = sum_k A[m,k]*W[n,k].  MODE 0: bf16(Y*scale). MODE 2: f32(Y)+res.
// ---------------------------------------------------------------------------
template<int BM, int MODE>
__device__ __forceinline__ void gemm_body(const unsigned short* __restrict__ A,
    const unsigned short* __restrict__ W, void* __restrict__ outp,
    const float* __restrict__ res, float scale, int m0, int n0)
{
  constexpr int MF = BM/32;               // fragment rows per wave
  __shared__ unsigned short lA[BM*64];
  __shared__ unsigned short lB[128*64];
  const int t = threadIdx.x, wv = t >> 6, lane = t & 63;
  const int wm = wv >> 1, wn = wv & 1;
  const int lr = lane & 15, kg = lane >> 4;
  const int lrow = lane >> 3, sch = (lane & 7) ^ lrow;   // src pre-swizzle

  f32x4 acc[MF][4];
#pragma unroll
  for (int i = 0; i < MF; ++i)
#pragma unroll
    for (int j = 0; j < 4; ++j) { acc[i][j][0]=0.f; acc[i][j][1]=0.f; acc[i][j][2]=0.f; acc[i][j][3]=0.f; }

  for (int kt = 0; kt < 1024; kt += 64) {
#pragma unroll
    for (int ii = 0; ii < BM/32; ++ii) {
      const int inst = wv*(BM/32) + ii;
      const int row  = inst*8 + lrow;
      gload_lds16(A + (size_t)(m0+row)*1024 + kt + sch*8, lA + inst*512);
    }
#pragma unroll
    for (int ii = 0; ii < 4; ++ii) {
      const int inst = wv*4 + ii;
      const int row  = inst*8 + lrow;
      gload_lds16(W + (size_t)(n0+row)*1024 + kt + sch*8, lB + inst*512);
    }
    __syncthreads();

    s16x8 a0[MF], a1[MF], b0[4], b1[4];
#pragma unroll
    for (int mf = 0; mf < MF; ++mf) {
      int row = wm*(BM/2) + mf*16 + lr, s7 = row & 7;
      a0[mf] = *(const s16x8*)(lA + row*64 + ((kg^s7)*8));
      a1[mf] = *(const s16x8*)(lA + row*64 + (((kg+4)^s7)*8));
    }
#pragma unroll
    for (int nf = 0; nf < 4; ++nf) {
      int row = wn*64 + nf*16 + lr, s7 = row & 7;
      b0[nf] = *(const s16x8*)(lB + row*64 + ((kg^s7)*8));
      b1[nf] = *(const s16x8*)(lB + row*64 + (((kg+4)^s7)*8));
    }
#pragma unroll
    for (int mf = 0; mf < MF; ++mf)
#pragma unroll
      for (int nf = 0; nf < 4; ++nf) {
        acc[mf][nf] = __builtin_amdgcn_mfma_f32_16x16x32_bf16(a0[mf], b0[nf], acc[mf][nf], 0,0,0);
        acc[mf][nf] = __builtin_amdgcn_mfma_f32_16x16x32_bf16(a1[mf], b1[nf], acc[mf][nf], 0,0,0);
      }
    __syncthreads();
  }

#pragma unroll
  for (int mf = 0; mf < MF; ++mf)
#pragma unroll
    for (int nf = 0; nf < 4; ++nf)
#pragma unroll
      for (int r = 0; r < 4; ++r) {
        int grow = m0 + wm*(BM/2) + mf*16 + kg*4 + r;   // C/D: row=(lane>>4)*4+reg
        int gcol = n0 + wn*64 + nf*16 + lr;             //      col=lane&15
        size_t o = (size_t)grow*1024 + gcol;
        float v = acc[mf][nf][r];
        if (MODE == 0) ((unsigned short*)outp)[o] = f2bf(v*scale);
        else           ((float*)outp)[o] = v + res[o];
      }
}

__global__ __launch_bounds__(256)
void gemm_qkv(const unsigned short* __restrict__ xb,
              const unsigned short* __restrict__ wq, const unsigned short* __restrict__ wk,
              const unsigned short* __restrict__ wv_,
              unsigned short* __restrict__ Qb, unsigned short* __restrict__ Kb,
              unsigned short* __restrict__ Vb)
{
  const int z = blockIdx.z;
  const unsigned short* W = (z==0)?wq:((z==1)?wk:wv_);
  unsigned short* O = (z==0)?Qb:((z==1)?Kb:Vb);
  const float scale = (z==0) ? 0.125f : 1.0f;
  gemm_body<128,0>(xb, W, O, nullptr, scale, blockIdx.x*128, blockIdx.y*128);
}

__global__ __launch_bounds__(256)
void gemm_o(const unsigned short* __restrict__ Ab, const unsigned short* __restrict__ wo,
            float* __restrict__ out, const float* __restrict__ x)
{
  gemm_body<64,2>(Ab, wo, out, x, 1.0f, blockIdx.x*64, blockIdx.y*128);
}

// ---------------------------------------------------------------------------
// Exact f32 dot products for the 2 phase-relevant V columns per head.
// ---------------------------------------------------------------------------
__global__ __launch_bounds__(256)
void v01_kernel(const float* __restrict__ x, const float* __restrict__ Wv,
                float* __restrict__ V01)
{
  const int t = threadIdx.x;
  const int colid = t & 31;               // h = colid>>1, comp = colid&1
  const int row = blockIdx.x*8 + (t >> 5);
  const int wcol = (colid >> 1)*DK_ + (colid & 1);
  const float4* xr = (const float4*)(x  + (size_t)row*1024);
  const float4* wr = (const float4*)(Wv + (size_t)wcol*1024);
  float acc = 0.f;
  for (int k = 0; k < 256; ++k) {
    float4 a = xr[k], b = wr[k];
    acc += a.x*b.x + a.y*b.y + a.z*b.z + a.w*b.w;
  }
  V01[(size_t)row*32 + colid] = acc;
}

// phase init + exact cos/sin (cos(atan2(a,c)) = c/r, sin = a/r)
__global__ void phase_init2(const float* __restrict__ V01, float* __restrict__ ph,
                            float* __restrict__ cw, float* __restrict__ sw)
{
  int idx = blockIdx.x*256 + threadIdx.x;  // over B*H*T
  int tt = idx & (T_-1);
  int bh = idx >> 11;
  int b = bh >> 4, h = bh & 15;
  float a = V01[((size_t)(b*T_ + tt))*32 + h*2 + 0];
  float c = V01[((size_t)(b*T_ + tt))*32 + h*2 + 1] + 1e-8f;
  ph[idx] = atan2f(a, c);
  float r = fmaxf(sqrtf(a*a + c*c), 1e-30f);
  cw[idx] = c / r;
  sw[idx] = a / r;
}

// ---------------------------------------------------------------------------
// build_cse: J[i][j] = fp8(exp(q_i.k_j/8)) with CLEAN writes + step-1 C/S/E
// partials.  Wave exclusively owns 32 i-rows x one 512-j chunk, walks j in
// 64-j groups.  Swapped MFMA -> lane(lr,kg) has j=s*16+kg*4+r for i=lr; an
// in-register 4x4 transpose across kg lanes (shfl_xor 16/32) gives each lane
// 16 CONTIGUOUS bytes -> one uint4 store completes full 64B sectors in a
// single instruction (no partial-line eviction -> no write amplification).
// C/S/E chunk-partials -> parts[3][4][BH*T] (deterministic, no atomics).
// Grid (T/128, 4, BH), 4 waves.
// ---------------------------------------------------------------------------
__global__ __launch_bounds__(256, 4)
void build_cse(const unsigned short* __restrict__ Qb, const unsigned short* __restrict__ Kb,
               unsigned char* __restrict__ J,
               const float* __restrict__ cr, const float* __restrict__ sr,
               float* __restrict__ parts)
{
  const int ib = blockIdx.x;              // i-block of 128
  const int jc = blockIdx.y;              // j-chunk of 512
  const int bh = blockIdx.z;
  const int b = bh >> 4, h = bh & 15;
  const int wv = threadIdx.x >> 6, lane = threadIdx.x & 63;
  const int lr = lane & 15, kg = lane >> 4;
  const int i0 = ib*128 + wv*32;          // wave's 32 rows

  s16x8 bq0[2], bq1[2];
#pragma unroll
  for (int it = 0; it < 2; ++it) {
    const unsigned short* qrow = Qb + ((size_t)(b*T_ + i0 + it*16 + lr))*D_ + h*DK_;
    bq0[it] = *(const s16x8*)(qrow + kg*8);
    bq1[it] = *(const s16x8*)(qrow + 32 + kg*8);
  }
  const unsigned short* Kbase = Kb + (size_t)b*T_*D_ + h*DK_;
  const float* crow = cr + (size_t)bh*T_;
  const float* srow = sr + (size_t)bh*T_;

  float Cp[2] = {0.f,0.f}, Sp[2] = {0.f,0.f}, Ep[2] = {0.f,0.f};

  const int jbeg = jc*512;
  for (int j0 = jbeg; j0 < jbeg + 512; j0 += 64) {
    s16x8 ak0[4], ak1[4];
    float4 cj[4], sj[4];
#pragma unroll
    for (int s = 0; s < 4; ++s) {
      const unsigned short* krow = Kbase + (size_t)(j0 + s*16 + lr)*D_;
      ak0[s] = *(const s16x8*)(krow + kg*8);
      ak1[s] = *(const s16x8*)(krow + 32 + kg*8);
      cj[s] = *(const float4*)(crow + j0 + s*16 + kg*4);
      sj[s] = *(const float4*)(srow + j0 + s*16 + kg*4);
    }
#pragma unroll
    for (int it = 0; it < 2; ++it) {
      unsigned int pk[4];
#pragma unroll
      for (int s = 0; s < 4; ++s) {
        f32x4 dd; dd[0]=0.f; dd[1]=0.f; dd[2]=0.f; dd[3]=0.f;
        dd = __builtin_amdgcn_mfma_f32_16x16x32_bf16(ak0[s], bq0[it], dd, 0, 0, 0);
        dd = __builtin_amdgcn_mfma_f32_16x16x32_bf16(ak1[s], bq1[it], dd, 0, 0, 0);
        float e0 = __expf(dd[0]), e1 = __expf(dd[1]);
        float e2 = __expf(dd[2]), e3 = __expf(dd[3]);
        unsigned int p = 0;
        p = __builtin_amdgcn_cvt_pk_fp8_f32(e0, e1, p, false);
        p = __builtin_amdgcn_cvt_pk_fp8_f32(e2, e3, p, true);
        pk[s] = p;
        Cp[it] += e0*cj[s].x + e1*cj[s].y + e2*cj[s].z + e3*cj[s].w;
        Sp[it] += e0*sj[s].x + e1*sj[s].y + e2*sj[s].z + e3*sj[s].w;
        Ep[it] += (e0 + e1) + (e2 + e3);
      }
      // 4x4 transpose over (reg s <-> kg lane): X[kg][s] = V[s][kg]
      {
        unsigned int o[4];
#pragma unroll
        for (int s = 0; s < 4; ++s) o[s] = __shfl_xor(pk[s^1], 16);
#pragma unroll
        for (int s = 0; s < 4; ++s) if ((s & 1) != (kg & 1)) pk[s] = o[s];
#pragma unroll
        for (int s = 0; s < 4; ++s) o[s] = __shfl_xor(pk[s^2], 32);
#pragma unroll
        for (int s = 0; s < 4; ++s) if (((s>>1)&1) != ((kg>>1)&1)) pk[s] = o[s];
      }
      uint4 st; st.x = pk[0]; st.y = pk[1]; st.z = pk[2]; st.w = pk[3];
      *(uint4*)(J + ((size_t)(bh*T_ + i0 + it*16 + lr))*T_ + j0 + kg*16) = st;
    }
  }

  // reduce over kg lanes (bits 4,5); lr-lanes hold distinct rows
#pragma unroll
  for (int m = 16; m < 64; m <<= 1)
#pragma unroll
    for (int it = 0; it < 2; ++it) {
      Cp[it] += __shfl_xor(Cp[it], m);
      Sp[it] += __shfl_xor(Sp[it], m);
      Ep[it] += __shfl_xor(Ep[it], m);
    }
  if (kg == 0) {
    const size_t N = (size_t)BH_*T_;
#pragma unroll
    for (int it = 0; it < 2; ++it) {
      size_t row = (size_t)bh*T_ + i0 + it*16 + lr;
      parts[(0*4 + jc)*N + row] = Cp[it];
      parts[(1*4 + jc)*N + row] = Sp[it];
      parts[(2*4 + jc)*N + row] = Ep[it];
    }
  }
}

// finalize step 1: sum 4 chunk-partials, update phase, emit cos/sin
__global__ void finalize1(const float* __restrict__ parts,
                          const float* __restrict__ cr, const float* __restrict__ sr,
                          float* __restrict__ cw, float* __restrict__ sw,
                          float* __restrict__ ph, const float* __restrict__ omega)
{
  int idx = blockIdx.x*256 + threadIdx.x;   // over BH*T
  const size_t N = (size_t)BH_*T_;
  float C = parts[0*N+idx] + parts[1*N+idx] + parts[2*N+idx] + parts[3*N+idx];
  float S = parts[4*N+idx] + parts[5*N+idx] + parts[6*N+idx] + parts[7*N+idx];
  float E = parts[8*N+idx] + parts[9*N+idx] + parts[10*N+idx] + parts[11*N+idx];
  int bh = idx >> 11;
  float si = sr[idx], ci = cr[idx];
  float coupling = (si*C - ci*S) / E;
  float pn = ph[idx] + DT_*(omega[bh & 15] + coupling);
  pn = fmodf(pn, TWO_PI_F);
  if (pn < 0.f) pn += TWO_PI_F;             // numpy mod semantics
  ph[idx] = pn;
  cw[idx] = __cosf(pn);
  sw[idx] = __sinf(pn);
}

// ---------------------------------------------------------------------------
// j_step2: streaming Kuramoto step (uint4 J loads, 4 rows/wave, f32x2
// accumulators -> v_pk_fma_f32; cos/sin double-buffered, epilogue writes
// next step's cos/sin).
// ---------------------------------------------------------------------------
__global__ __launch_bounds__(256)
void j_step2(const unsigned char* __restrict__ J,
             const float* __restrict__ cr, const float* __restrict__ sr,
             float* __restrict__ cw, float* __restrict__ sw,
             float* __restrict__ ph, const float* __restrict__ omega)
{
  const int wv = threadIdx.x >> 6, lane = threadIdx.x & 63;
  const int r0 = (blockIdx.x*4 + wv)*4;      // 4 rows per wave, rows = bh*T+t
  const int bh = r0 >> 11;
  const float4* c4 = (const float4*)(cr + (size_t)bh*T_);
  const float4* s4 = (const float4*)(sr + (size_t)bh*T_);

  f32x2 C2[4], S2[4], E2[4];
#pragma unroll
  for (int r = 0; r < 4; ++r) { C2[r][0]=0.f; C2[r][1]=0.f; S2[r][0]=0.f; S2[r][1]=0.f; E2[r][0]=0.f; E2[r][1]=0.f; }

#pragma unroll
  for (int k = 0; k < 2; ++k) {
    int idx = k*64 + lane;                   // uint4 index (16 fp8 = 16 j)
    f32x2 clo[4], chi[4], slo[4], shi[4];
#pragma unroll
    for (int q = 0; q < 4; ++q) {
      float4 cv = c4[idx*4+q], sv = s4[idx*4+q];
      clo[q][0]=cv.x; clo[q][1]=cv.y; chi[q][0]=cv.z; chi[q][1]=cv.w;
      slo[q][0]=sv.x; slo[q][1]=sv.y; shi[q][0]=sv.z; shi[q][1]=sv.w;
    }
#pragma unroll
    for (int row = 0; row < 4; ++row) {
      uint4 jv = *(const uint4*)(J + (size_t)(r0+row)*T_ + (size_t)idx*16);
#pragma unroll
      for (int q = 0; q < 4; ++q) {
        unsigned int wq_ = (q==0)?jv.x:(q==1)?jv.y:(q==2)?jv.z:jv.w;
        f32x2 lo = __builtin_amdgcn_cvt_pk_f32_fp8(wq_, false);
        f32x2 hi = __builtin_amdgcn_cvt_pk_f32_fp8(wq_, true);
        C2[row] += lo*clo[q] + hi*chi[q];
        S2[row] += lo*slo[q] + hi*shi[q];
        E2[row] += lo + hi;
      }
    }
  }

  float C[4], S[4], E[4];
#pragma unroll
  for (int r = 0; r < 4; ++r) { C[r]=C2[r][0]+C2[r][1]; S[r]=S2[r][0]+S2[r][1]; E[r]=E2[r][0]+E2[r][1]; }

#pragma unroll
  for (int m = 1; m < 64; m <<= 1) {
#pragma unroll
    for (int row = 0; row < 4; ++row) {
      C[row] += __shfl_xor(C[row], m);
      S[row] += __shfl_xor(S[row], m);
      E[row] += __shfl_xor(E[row], m);
    }
  }

  if (lane < 4) {
    float Cc = (lane==0)?C[0]:(lane==1)?C[1]:(lane==2)?C[2]:C[3];
    float Ss = (lane==0)?S[0]:(lane==1)?S[1]:(lane==2)?S[2]:S[3];
    float Ee = (lane==0)?E[0]:(lane==1)?E[1]:(lane==2)?E[2]:E[3];
    int pidx = r0 + lane;
    float si = sr[pidx], ci = cr[pidx];
    float om = omega[bh & 15];
    float coupling = (si*Cc - ci*Ss) / Ee;
    float pn = ph[pidx] + DT_*(om + coupling);
    pn = fmodf(pn, TWO_PI_F);
    if (pn < 0.f) pn += TWO_PI_F;
    ph[pidx] = pn;
    cw[pidx] = __cosf(pn);
    sw[pidx] = __sinf(pn);
  }
}

// vmod: V *= cos(phase_final) in bf16 (reads final cos buffer)
__global__ void vmod2(unsigned short* __restrict__ V, const float* __restrict__ cfin)
{
  int idx = blockIdx.x*256 + threadIdx.x;    // over M_*D_/8
  int row = idx >> 7;           // b*T + t
  int g = idx & 127;
  int h = g >> 3;               // 8 s16x8 groups per head
  int b = row >> 11, tt = row & 2047;
  float c = cfin[((size_t)(b*H_ + h))*T_ + tt];
  s16x8 v = *(s16x8*)(V + (size_t)idx*8);
  s16x8 o;
#pragma unroll
  for (int e = 0; e < 8; ++e) {
    float f = __uint_as_float(((unsigned int)(unsigned short)v[e]) << 16);
    o[e] = (short)f2bf(f * c);
  }
  *(s16x8*)(V + (size_t)idx*8) = o;
}

// ---------------------------------------------------------------------------
extern "C" void kernel_launch(void* const* d_in, const int* in_sizes, int n_in,
                              void* d_out, int out_size, void* d_ws, size_t ws_size,
                              hipStream_t stream)
{
  const float* x     = (const float*)d_in[0];
  const float* Wq    = (const float*)d_in[1];
  const float* Wk    = (const float*)d_in[2];
  const float* Wv    = (const float*)d_in[3];
  const float* Wo    = (const float*)d_in[4];
  const float* omega = (const float*)d_in[5];
  float* out = (float*)d_out;

  // workspace carve (~153 MiB; J aliases dead xb/wqb/wkb/wvb)
  char* w = (char*)d_ws;
  unsigned short* Qb  = (unsigned short*)w; w += (size_t)M_*D_*2;   // bf16, pre-scaled 1/8
  unsigned short* Kb  = (unsigned short*)w; w += (size_t)M_*D_*2;
  unsigned short* Vb  = (unsigned short*)w; w += (size_t)M_*D_*2;   // bf16 V (vmod in place)
  unsigned short* wob = (unsigned short*)w; w += (size_t)D_*D_*2;
  float* ph   = (float*)w; w += (size_t)BH_*T_*4;
  float* csb[2]; float* snb[2];
  csb[0] = (float*)w; w += (size_t)BH_*T_*4;
  snb[0] = (float*)w; w += (size_t)BH_*T_*4;
  csb[1] = (float*)w; w += (size_t)BH_*T_*4;
  snb[1] = (float*)w; w += (size_t)BH_*T_*4;
  float* V01   = (float*)w; w += (size_t)M_*32*4;
  float* parts = (float*)w; w += (size_t)3*4*BH_*T_*4;              // 3 MiB
  unsigned char* J = (unsigned char*)w;                             // 128 MiB
  // aliased into J's head (dead once build_cse runs):
  unsigned short* xb  = (unsigned short*)J;                         // 8 MiB
  unsigned short* wqb = (unsigned short*)(J + (size_t)M_*D_*2);
  unsigned short* wkb = wqb + (size_t)D_*D_;
  unsigned short* wvb = wkb + (size_t)D_*D_;

  conv_all<<<4096, 256, 0, stream>>>(x, Wq, Wk, Wv, Wo, xb, wqb, wkb, wvb, wob);

  gemm_qkv<<<dim3(M_/128, D_/128, 3), 256, 0, stream>>>(xb, wqb, wkb, wvb, Qb, Kb, Vb);

  v01_kernel<<<M_/8, 256, 0, stream>>>(x, Wv, V01);
  phase_init2<<<BH_*T_/256, 256, 0, stream>>>(V01, ph, csb[0], snb[0]);

  // J materialization + step-1 partials (overwrites xb/wq/wk/wv alias region)
  build_cse<<<dim3(T_/128, 4, BH_), 256, 0, stream>>>(Qb, Kb, J, csb[0], snb[0], parts);
  finalize1<<<BH_*T_/256, 256, 0, stream>>>(parts, csb[0], snb[0], csb[1], snb[1], ph, omega);

  for (int s = 1; s < NSTEP; ++s)
    j_step2<<<BH_*T_/16, 256, 0, stream>>>(J, csb[s&1], snb[s&1],
                                           csb[(s+1)&1], snb[(s+1)&1], ph, omega);

  vmod2<<<M_*D_/8/256, 256, 0, stream>>>(Vb, csb[NSTEP&1]);
  gemm_o<<<dim3(M_/64, D_/128), 256, 0, stream>>>(Vb, wob, out, x);
}